// Round 3
// baseline (3822.956 us; speedup 1.0000x reference)
//
#include <hip/hip_runtime.h>
#include <hip/hip_bf16.h>

#define NN 100000
#define NE 1600000
#define NC 800000
#define D  32
#define DE 65
#define JB 72     // padded hidden dim for bf16 tables (144B rows, 16B-aligned)
#define KP 33     // LDS k-stride in precompute (odd -> conflict-free)
#define W1_LD 68  // fallback kernel stride

// ---- ws byte offsets (all 16B-aligned), total ~48.8 MB ----
#define OFF_ROW 0u                  // int[NN+1]   row_start
#define OFF_CNT 400016u             // int[NN]     counts / cursor
#define OFF_SC  800016u             // int2[NE]    (sender, coupling-bits)
#define OFF_SR  13600016u           // int[NE]     sorted receiver
#define OFF_A   20000016u           // bf16[NN*JB] A table (b1 folded)
#define OFF_B   34400016u           // bf16[NN*JB] B table
#define WS_NEED 48800016u

__device__ __forceinline__ float selu_f(float x) {
    const float scale = 1.0507009873554805f;
    const float alpha = 1.6732632423543772f;
    return x > 0.0f ? scale * x : scale * alpha * (__expf(x) - 1.0f);
}

__device__ __forceinline__ float2 bf2(unsigned int u) {
    // two packed bf16 -> two floats (element 0 in low 16 bits)
    return make_float2(__uint_as_float(u << 16), __uint_as_float(u & 0xffff0000u));
}

// ---------------- CSR build ----------------
__global__ __launch_bounds__(256) void hist_kernel(
    const int* __restrict__ receivers, int* __restrict__ counts)
{
    const int e = blockIdx.x * 256 + threadIdx.x;
    atomicAdd(&counts[receivers[e]], 1);
}

__global__ __launch_bounds__(1024) void scan_kernel(
    const int* __restrict__ counts, int* __restrict__ row_start)
{
    __shared__ int ssum[1024];
    const int tid = threadIdx.x;
    const int chunk = (NN + 1023) / 1024;           // 98
    const int lo = tid * chunk;
    const int hi = lo + chunk < NN ? lo + chunk : NN;
    int s = 0;
    for (int i = lo; i < hi; ++i) s += counts[i];
    ssum[tid] = s;
    __syncthreads();
    for (int off = 1; off < 1024; off <<= 1) {      // inclusive scan
        int v = (tid >= off) ? ssum[tid - off] : 0;
        __syncthreads();
        ssum[tid] += v;
        __syncthreads();
    }
    int off = ssum[tid] - s;                        // exclusive base for this chunk
    for (int i = lo; i < hi; ++i) { row_start[i] = off; off += counts[i]; }
    if (tid == 0) row_start[NN] = ssum[1023];
}

__global__ __launch_bounds__(256) void scatter_kernel(
    const int* __restrict__ senders, const int* __restrict__ receivers,
    const float* __restrict__ coup,
    const int* __restrict__ row_start, int* __restrict__ cursor,
    int2* __restrict__ sorted_sc, int* __restrict__ sorted_r)
{
    const int e = blockIdx.x * 256 + threadIdx.x;
    const int r = receivers[e];
    const float c = coup[e < NC ? e : e - NC];
    const int pos = atomicAdd(&cursor[r], 1);
    const int i = row_start[r] + pos;
    sorted_sc[i] = make_int2(senders[e], __float_as_int(c));
    sorted_r[i] = r;
}

// ---------------- per-node layer-1 halves, bf16 ----------------
// A[n][j] = b1[j] + sum_k h[n][k]*W1[k][j]      (k in [0,32))
// B[n][j] =          sum_k h[n][k]*W1[32+k][j]
__global__ __launch_bounds__(256) void precompute_kernel(
    const float* __restrict__ h, const float* __restrict__ W1,
    const float* __restrict__ b1,
    __hip_bfloat16* __restrict__ A, __hip_bfloat16* __restrict__ B)
{
    __shared__ float sWA[JB * KP];
    __shared__ float sWB[JB * KP];
    __shared__ float sb1[JB];
    for (int i = threadIdx.x; i < JB * 32; i += 256) {
        int j = i >> 5, k = i & 31;
        sWA[j * KP + k] = (j < DE) ? W1[k * DE + j] : 0.f;
        sWB[j * KP + k] = (j < DE) ? W1[(k + 32) * DE + j] : 0.f;
    }
    if (threadIdx.x < JB) sb1[threadIdx.x] = (threadIdx.x < DE) ? b1[threadIdx.x] : 0.f;
    __syncthreads();

    const int idx = blockIdx.x * 256 + threadIdx.x;   // grid covers NN*JB exactly
    const int n = idx / JB;
    const int j = idx - n * JB;
    const float4* hr = reinterpret_cast<const float4*>(h + (size_t)n * D);
    const float* wa = &sWA[j * KP];
    const float* wb = &sWB[j * KP];
    float a = sb1[j], b = 0.f;
    #pragma unroll
    for (int kk = 0; kk < 8; ++kk) {
        float4 hv = hr[kk];
        a = fmaf(hv.x, wa[4*kk+0], a); a = fmaf(hv.y, wa[4*kk+1], a);
        a = fmaf(hv.z, wa[4*kk+2], a); a = fmaf(hv.w, wa[4*kk+3], a);
        b = fmaf(hv.x, wb[4*kk+0], b); b = fmaf(hv.y, wb[4*kk+1], b);
        b = fmaf(hv.z, wb[4*kk+2], b); b = fmaf(hv.w, wb[4*kk+3], b);
    }
    A[idx] = __float2bfloat16(j < DE ? a : 0.f);
    B[idx] = __float2bfloat16(j < DE ? b : 0.f);
}

// ---------------- main edge kernel (receiver-sorted) ----------------
__global__ __launch_bounds__(256) void edge_csr_kernel(
    const int2* __restrict__ sorted_sc, const int* __restrict__ sorted_r,
    const __hip_bfloat16* __restrict__ Atab, const __hip_bfloat16* __restrict__ Btab,
    const float* __restrict__ W1, const float* __restrict__ W2,
    const float* __restrict__ b2, float* __restrict__ out)
{
    __shared__ float sW2[JB * D];     // rows j>=65 zero
    __shared__ float sw1c[JB];
    __shared__ float sb2[D];
    for (int i = threadIdx.x; i < JB * D; i += 256) {
        int j = i >> 5;
        sW2[i] = (j < DE) ? W2[j * D + (i & 31)] : 0.f;
    }
    if (threadIdx.x < JB) sw1c[threadIdx.x] = (threadIdx.x < DE) ? W1[64 * DE + threadIdx.x] : 0.f;
    if (threadIdx.x >= 128 && threadIdx.x < 128 + D) sb2[threadIdx.x - 128] = b2[threadIdx.x - 128];
    __syncthreads();

    const int e = blockIdx.x * 256 + threadIdx.x;     // grid covers NE exactly
    const int2 sc = sorted_sc[e];
    const int s = sc.x;
    const float c = __int_as_float(sc.y);
    const int r = sorted_r[e];

    const uint4* Ar = reinterpret_cast<const uint4*>(Atab + (size_t)r * JB);
    const uint4* Bs = reinterpret_cast<const uint4*>(Btab + (size_t)s * JB);

    float acc[D];
    #pragma unroll
    for (int d2 = 0; d2 < D; ++d2) acc[d2] = sb2[d2];

    uint4 a_cur = Ar[0], b_cur = Bs[0];
    #pragma unroll 1
    for (int i = 0; i < 9; ++i) {                     // 9 x (8 hidden units)
        uint4 a_nxt, b_nxt;
        if (i < 8) { a_nxt = Ar[i + 1]; b_nxt = Bs[i + 1]; }

        const float4* w1c4 = reinterpret_cast<const float4*>(&sw1c[8 * i]);
        float4 wv0 = w1c4[0], wv1 = w1c4[1];
        float2 a01 = bf2(a_cur.x), a23 = bf2(a_cur.y), a45 = bf2(a_cur.z), a67 = bf2(a_cur.w);
        float2 b01 = bf2(b_cur.x), b23 = bf2(b_cur.y), b45 = bf2(b_cur.z), b67 = bf2(b_cur.w);
        float hv[8];
        hv[0] = selu_f(fmaf(c, wv0.x, a01.x + b01.x));
        hv[1] = selu_f(fmaf(c, wv0.y, a01.y + b01.y));
        hv[2] = selu_f(fmaf(c, wv0.z, a23.x + b23.x));
        hv[3] = selu_f(fmaf(c, wv0.w, a23.y + b23.y));
        hv[4] = selu_f(fmaf(c, wv1.x, a45.x + b45.x));
        hv[5] = selu_f(fmaf(c, wv1.y, a45.y + b45.y));
        hv[6] = selu_f(fmaf(c, wv1.z, a67.x + b67.x));
        hv[7] = selu_f(fmaf(c, wv1.w, a67.y + b67.y));

        #pragma unroll
        for (int jj = 0; jj < 8; ++jj) {
            const float4* w2r = reinterpret_cast<const float4*>(&sW2[(8 * i + jj) * D]);
            const float hj = hv[jj];
            #pragma unroll
            for (int dq = 0; dq < 8; ++dq) {
                float4 w = w2r[dq];
                acc[4*dq+0] = fmaf(hj, w.x, acc[4*dq+0]);
                acc[4*dq+1] = fmaf(hj, w.y, acc[4*dq+1]);
                acc[4*dq+2] = fmaf(hj, w.z, acc[4*dq+2]);
                acc[4*dq+3] = fmaf(hj, w.w, acc[4*dq+3]);
            }
        }
        a_cur = a_nxt; b_cur = b_nxt;
    }

    float* op = out + (size_t)r * D;
    #pragma unroll
    for (int d2 = 0; d2 < D; ++d2) unsafeAtomicAdd(op + d2, selu_f(acc[d2]));
}

// ---------------- fallback (ws too small): monolithic round-1 kernel ----------
__global__ __launch_bounds__(256) void edge_msg_fallback(
    const float* __restrict__ h, const float* __restrict__ coup,
    const float* __restrict__ W1, const float* __restrict__ b1,
    const float* __restrict__ W2, const float* __restrict__ b2,
    const int* __restrict__ senders, const int* __restrict__ receivers,
    float* __restrict__ out)
{
    __shared__ float sW1t[DE * W1_LD];
    __shared__ float sW2[DE * D];
    __shared__ float sb1[DE];
    __shared__ float sb2[D];
    for (int i = threadIdx.x; i < DE * DE; i += 256) {
        int k = i / DE, j = i - k * DE;
        sW1t[j * W1_LD + k] = W1[i];
    }
    for (int i = threadIdx.x; i < DE * D; i += 256) sW2[i] = W2[i];
    if (threadIdx.x < DE) sb1[threadIdx.x] = b1[threadIdx.x];
    if (threadIdx.x >= 128 && threadIdx.x < 128 + D) sb2[threadIdx.x - 128] = b2[threadIdx.x - 128];
    __syncthreads();
    const int e = blockIdx.x * 256 + threadIdx.x;
    const int s = senders[e];
    const int r = receivers[e];
    float edgef[DE];
    const float4* hr = reinterpret_cast<const float4*>(h + (size_t)r * D);
    const float4* hs = reinterpret_cast<const float4*>(h + (size_t)s * D);
    #pragma unroll
    for (int i = 0; i < 8; ++i) {
        float4 v = hr[i];
        edgef[4*i] = v.x; edgef[4*i+1] = v.y; edgef[4*i+2] = v.z; edgef[4*i+3] = v.w;
    }
    #pragma unroll
    for (int i = 0; i < 8; ++i) {
        float4 v = hs[i];
        edgef[D+4*i] = v.x; edgef[D+4*i+1] = v.y; edgef[D+4*i+2] = v.z; edgef[D+4*i+3] = v.w;
    }
    edgef[2*D] = coup[e < NC ? e : e - NC];
    float acc[D];
    #pragma unroll
    for (int d2 = 0; d2 < D; ++d2) acc[d2] = sb2[d2];
    for (int j = 0; j < DE; ++j) {
        const float* wrow = &sW1t[j * W1_LD];
        float p0 = 0.f, p1 = 0.f, p2 = 0.f, p3 = 0.f;
        #pragma unroll
        for (int k = 0; k < 64; k += 4) {
            p0 = fmaf(edgef[k], wrow[k], p0);
            p1 = fmaf(edgef[k+1], wrow[k+1], p1);
            p2 = fmaf(edgef[k+2], wrow[k+2], p2);
            p3 = fmaf(edgef[k+3], wrow[k+3], p3);
        }
        float hj = selu_f(sb1[j] + fmaf(edgef[64], wrow[64], (p0+p1)+(p2+p3)));
        const float* w2row = &sW2[j * D];
        #pragma unroll
        for (int d2 = 0; d2 < D; ++d2) acc[d2] = fmaf(hj, w2row[d2], acc[d2]);
    }
    float* op = out + (size_t)r * D;
    #pragma unroll
    for (int d2 = 0; d2 < D; ++d2) unsafeAtomicAdd(op + d2, selu_f(acc[d2]));
}

__global__ __launch_bounds__(256) void relu_kernel(float* __restrict__ out) {
    const int i = blockIdx.x * 256 + threadIdx.x;
    float4* p = reinterpret_cast<float4*>(out);
    float4 v = p[i];
    v.x = fmaxf(v.x, 0.f); v.y = fmaxf(v.y, 0.f);
    v.z = fmaxf(v.z, 0.f); v.w = fmaxf(v.w, 0.f);
    p[i] = v;
}

extern "C" void kernel_launch(void* const* d_in, const int* in_sizes, int n_in,
                              void* d_out, int out_size, void* d_ws, size_t ws_size,
                              hipStream_t stream) {
    const float* h    = (const float*)d_in[0];
    const float* coup = (const float*)d_in[1];
    const float* W1   = (const float*)d_in[2];
    const float* b1   = (const float*)d_in[3];
    const float* W2   = (const float*)d_in[4];
    const float* b2   = (const float*)d_in[5];
    // d_in[6..9] = Wq, bq, Wk, bk: unused — softmax over a size-1 axis is 1.0
    const int* senders   = (const int*)d_in[10];
    const int* receivers = (const int*)d_in[11];
    float* out = (float*)d_out;

    hipMemsetAsync(d_out, 0, (size_t)out_size * sizeof(float), stream);

    if (ws_size >= (size_t)WS_NEED) {
        char* ws = (char*)d_ws;
        int*  row_start = (int*)(ws + OFF_ROW);
        int*  counts    = (int*)(ws + OFF_CNT);
        int2* sorted_sc = (int2*)(ws + OFF_SC);
        int*  sorted_r  = (int*)(ws + OFF_SR);
        __hip_bfloat16* Atab = (__hip_bfloat16*)(ws + OFF_A);
        __hip_bfloat16* Btab = (__hip_bfloat16*)(ws + OFF_B);

        hipMemsetAsync(counts, 0, NN * sizeof(int), stream);
        hist_kernel<<<NE / 256, 256, 0, stream>>>(receivers, counts);
        scan_kernel<<<1, 1024, 0, stream>>>(counts, row_start);
        hipMemsetAsync(counts, 0, NN * sizeof(int), stream);   // reuse as cursor
        scatter_kernel<<<NE / 256, 256, 0, stream>>>(
            senders, receivers, coup, row_start, counts, sorted_sc, sorted_r);
        precompute_kernel<<<NN * JB / 256, 256, 0, stream>>>(h, W1, b1, Atab, Btab);
        edge_csr_kernel<<<NE / 256, 256, 0, stream>>>(
            sorted_sc, sorted_r, Atab, Btab, W1, W2, b2, out);
    } else {
        edge_msg_fallback<<<NE / 256, 256, 0, stream>>>(
            h, coup, W1, b1, W2, b2, senders, receivers, out);
    }
    relu_kernel<<<out_size / 4 / 256, 256, 0, stream>>>(out);
}

// Round 4
// 720.623 us; speedup vs baseline: 5.3051x; 5.3051x over previous
//
#include <hip/hip_runtime.h>
#include <hip/hip_bf16.h>

#define NN 100000
#define NE 1600000
#define NC 800000
#define D  32
#define DE 65
#define JB 72     // bf16 elements per table row (144B, 16B-aligned)
#define JBU 36    // uints per table row
#define KP 33     // LDS k-stride in precompute
#define W1_LD 68  // fallback kernel stride

// ---- ws byte offsets (16B-aligned) ----
#define OFF_ROW 0u                  // int[NN+1]    row_start
#define OFF_CNT 400016u             // int[NN]      counts / cursor
#define OFF_SC  800016u             // int2[NE]     (sender, coupling-bits), receiver-sorted
#define OFF_A   13600016u           // bf16[NN*JB]  A table (b1 folded)
#define OFF_B   28000016u           // bf16[NN*JB]  B table
#define WS_NEED 42400016u

__device__ __forceinline__ float selu_f(float x) {
    const float scale = 1.0507009873554805f;
    const float alpha = 1.6732632423543772f;
    return x > 0.0f ? scale * x : scale * alpha * (__expf(x) - 1.0f);
}

__device__ __forceinline__ float2 bf2(unsigned int u) {
    // two packed bf16 -> two floats (element 0 in low 16 bits)
    return make_float2(__uint_as_float(u << 16), __uint_as_float(u & 0xffff0000u));
}

// ---------------- CSR build ----------------
__global__ __launch_bounds__(256) void hist_kernel(
    const int* __restrict__ receivers, int* __restrict__ counts)
{
    const int e = blockIdx.x * 256 + threadIdx.x;
    atomicAdd(&counts[receivers[e]], 1);
}

__global__ __launch_bounds__(1024) void scan_kernel(
    const int* __restrict__ counts, int* __restrict__ row_start)
{
    __shared__ int ssum[1024];
    const int tid = threadIdx.x;
    const int chunk = (NN + 1023) / 1024;           // 98
    const int lo = tid * chunk;
    const int hi = lo + chunk < NN ? lo + chunk : NN;
    int s = 0;
    for (int i = lo; i < hi; ++i) s += counts[i];
    ssum[tid] = s;
    __syncthreads();
    for (int off = 1; off < 1024; off <<= 1) {      // inclusive scan
        int v = (tid >= off) ? ssum[tid - off] : 0;
        __syncthreads();
        ssum[tid] += v;
        __syncthreads();
    }
    int off = ssum[tid] - s;                        // exclusive base
    for (int i = lo; i < hi; ++i) { row_start[i] = off; off += counts[i]; }
    if (tid == 0) row_start[NN] = ssum[1023];
}

__global__ __launch_bounds__(256) void scatter_kernel(
    const int* __restrict__ senders, const int* __restrict__ receivers,
    const float* __restrict__ coup,
    const int* __restrict__ row_start, int* __restrict__ cursor,
    int2* __restrict__ sorted_sc)
{
    const int e = blockIdx.x * 256 + threadIdx.x;
    const int r = receivers[e];
    const float c = coup[e < NC ? e : e - NC];
    const int pos = atomicAdd(&cursor[r], 1);
    sorted_sc[row_start[r] + pos] = make_int2(senders[e], __float_as_int(c));
}

// ---------------- per-node layer-1 halves, bf16 ----------------
// A[n][j] = b1[j] + sum_k h[n][k]*W1[k][j]      (k in [0,32))
// B[n][j] =          sum_k h[n][k]*W1[32+k][j]
__global__ __launch_bounds__(256) void precompute_kernel(
    const float* __restrict__ h, const float* __restrict__ W1,
    const float* __restrict__ b1,
    __hip_bfloat16* __restrict__ A, __hip_bfloat16* __restrict__ B)
{
    __shared__ float sWA[JB * KP];
    __shared__ float sWB[JB * KP];
    __shared__ float sb1[JB];
    for (int i = threadIdx.x; i < JB * 32; i += 256) {
        int j = i >> 5, k = i & 31;
        sWA[j * KP + k] = (j < DE) ? W1[k * DE + j] : 0.f;
        sWB[j * KP + k] = (j < DE) ? W1[(k + 32) * DE + j] : 0.f;
    }
    if (threadIdx.x < JB) sb1[threadIdx.x] = (threadIdx.x < DE) ? b1[threadIdx.x] : 0.f;
    __syncthreads();

    const int idx = blockIdx.x * 256 + threadIdx.x;   // grid covers NN*JB exactly
    const int n = idx / JB;
    const int j = idx - n * JB;
    const float4* hr = reinterpret_cast<const float4*>(h + (size_t)n * D);
    const float* wa = &sWA[j * KP];
    const float* wb = &sWB[j * KP];
    float a = sb1[j], b = 0.f;
    #pragma unroll
    for (int kk = 0; kk < 8; ++kk) {
        float4 hv = hr[kk];
        a = fmaf(hv.x, wa[4*kk+0], a); a = fmaf(hv.y, wa[4*kk+1], a);
        a = fmaf(hv.z, wa[4*kk+2], a); a = fmaf(hv.w, wa[4*kk+3], a);
        b = fmaf(hv.x, wb[4*kk+0], b); b = fmaf(hv.y, wb[4*kk+1], b);
        b = fmaf(hv.z, wb[4*kk+2], b); b = fmaf(hv.w, wb[4*kk+3], b);
    }
    A[idx] = __float2bfloat16(j < DE ? a : 0.f);
    B[idx] = __float2bfloat16(j < DE ? b : 0.f);
}

// ---------------- node-centric edge kernel: one wave per receiver ----------------
__global__ __launch_bounds__(256) void node_gather_kernel(
    const int* __restrict__ row_start,
    const int2* __restrict__ sorted_sc,
    const unsigned int* __restrict__ Au,    // bf16-pair view of A table
    const unsigned int* __restrict__ Bu,    // bf16-pair view of B table
    const float* __restrict__ W1,
    const float* __restrict__ W2,
    const float* __restrict__ b2,
    float* __restrict__ out)
{
    __shared__ float hh[4][80];             // per-wave hidden buffer (66 used)

    const int lane = threadIdx.x & 63;
    const int wid  = threadIdx.x >> 6;
    const int n    = blockIdx.x * 4 + wid;  // grid covers NN exactly
    const int d    = lane & 31;
    const int half = lane >> 5;
    const int ll   = lane < 33 ? lane : 32; // h-producer index (j = 2*ll, 2*ll+1)

    // register-resident W2 half-column: w2c[k] = W2[half*32+k][d]
    float w2c[33];
    #pragma unroll
    for (int k = 0; k < 32; ++k) w2c[k] = W2[(half * 32 + k) * D + d];
    w2c[32] = half ? W2[64 * D + d] : 0.f;
    const float b2d = b2[d];

    const float w1c0 = W1[64 * DE + 2 * ll];                       // j=2*ll <= 64: in range
    const float w1c1 = (2 * ll + 1 < DE) ? W1[64 * DE + 2 * ll + 1] : 0.f;

    const float2 af = bf2(Au[(size_t)n * JBU + ll]);               // A[n][2ll], A[n][2ll+1]

    const int rbeg = row_start[n];
    const int rend = row_start[n + 1];

    float acc = 0.f;
    float* hhw = hh[wid];

    if (rbeg < rend) {
        int2 sc = sorted_sc[rbeg];
        unsigned bu = Bu[(size_t)sc.x * JBU + ll];
        for (int i = rbeg; i < rend; ++i) {
            int2 sc_n = sc;
            unsigned bu_n = 0u;
            if (i + 1 < rend) {                     // wave-uniform branch
                sc_n = sorted_sc[i + 1];
                bu_n = Bu[(size_t)sc_n.x * JBU + ll];
            }
            const float c = __int_as_float(sc.y);
            const float2 bf = bf2(bu);
            const float h0 = selu_f(fmaf(c, w1c0, af.x + bf.x));
            const float h1 = selu_f(fmaf(c, w1c1, af.y + bf.y));
            if (lane < 33)
                *reinterpret_cast<float2*>(&hhw[2 * lane]) = make_float2(h0, h1);

            float v = 0.f;
            const float4* h4 = reinterpret_cast<const float4*>(&hhw[half * 32]);
            #pragma unroll
            for (int t = 0; t < 8; ++t) {
                float4 hv = h4[t];
                v = fmaf(hv.x, w2c[4 * t + 0], v);
                v = fmaf(hv.y, w2c[4 * t + 1], v);
                v = fmaf(hv.z, w2c[4 * t + 2], v);
                v = fmaf(hv.w, w2c[4 * t + 3], v);
            }
            v = fmaf(hhw[64], w2c[32], v);          // j=64 term (0 for half 0)
            v += __shfl_xor(v, 32);                 // combine halves
            acc += selu_f(v + b2d);
            sc = sc_n; bu = bu_n;
        }
    }
    if (lane < 32) out[(size_t)n * D + lane] = fmaxf(acc, 0.f);
}

// ---------------- fallback (ws too small): monolithic round-1 kernel ----------
__global__ __launch_bounds__(256) void edge_msg_fallback(
    const float* __restrict__ h, const float* __restrict__ coup,
    const float* __restrict__ W1, const float* __restrict__ b1,
    const float* __restrict__ W2, const float* __restrict__ b2,
    const int* __restrict__ senders, const int* __restrict__ receivers,
    float* __restrict__ out)
{
    __shared__ float sW1t[DE * W1_LD];
    __shared__ float sW2[DE * D];
    __shared__ float sb1[DE];
    __shared__ float sb2[D];
    for (int i = threadIdx.x; i < DE * DE; i += 256) {
        int k = i / DE, j = i - k * DE;
        sW1t[j * W1_LD + k] = W1[i];
    }
    for (int i = threadIdx.x; i < DE * D; i += 256) sW2[i] = W2[i];
    if (threadIdx.x < DE) sb1[threadIdx.x] = b1[threadIdx.x];
    if (threadIdx.x >= 128 && threadIdx.x < 128 + D) sb2[threadIdx.x - 128] = b2[threadIdx.x - 128];
    __syncthreads();
    const int e = blockIdx.x * 256 + threadIdx.x;
    const int s = senders[e];
    const int r = receivers[e];
    float edgef[DE];
    const float4* hr = reinterpret_cast<const float4*>(h + (size_t)r * D);
    const float4* hs = reinterpret_cast<const float4*>(h + (size_t)s * D);
    #pragma unroll
    for (int i = 0; i < 8; ++i) {
        float4 v = hr[i];
        edgef[4*i] = v.x; edgef[4*i+1] = v.y; edgef[4*i+2] = v.z; edgef[4*i+3] = v.w;
    }
    #pragma unroll
    for (int i = 0; i < 8; ++i) {
        float4 v = hs[i];
        edgef[D+4*i] = v.x; edgef[D+4*i+1] = v.y; edgef[D+4*i+2] = v.z; edgef[D+4*i+3] = v.w;
    }
    edgef[2*D] = coup[e < NC ? e : e - NC];
    float acc[D];
    #pragma unroll
    for (int d2 = 0; d2 < D; ++d2) acc[d2] = sb2[d2];
    for (int j = 0; j < DE; ++j) {
        const float* wrow = &sW1t[j * W1_LD];
        float p0 = 0.f, p1 = 0.f, p2 = 0.f, p3 = 0.f;
        #pragma unroll
        for (int k = 0; k < 64; k += 4) {
            p0 = fmaf(edgef[k], wrow[k], p0);
            p1 = fmaf(edgef[k+1], wrow[k+1], p1);
            p2 = fmaf(edgef[k+2], wrow[k+2], p2);
            p3 = fmaf(edgef[k+3], wrow[k+3], p3);
        }
        float hj = selu_f(sb1[j] + fmaf(edgef[64], wrow[64], (p0+p1)+(p2+p3)));
        const float* w2row = &sW2[j * D];
        #pragma unroll
        for (int d2 = 0; d2 < D; ++d2) acc[d2] = fmaf(hj, w2row[d2], acc[d2]);
    }
    float* op = out + (size_t)r * D;
    #pragma unroll
    for (int d2 = 0; d2 < D; ++d2) unsafeAtomicAdd(op + d2, selu_f(acc[d2]));
}

__global__ __launch_bounds__(256) void relu_kernel(float* __restrict__ out) {
    const int i = blockIdx.x * 256 + threadIdx.x;
    float4* p = reinterpret_cast<float4*>(out);
    float4 v = p[i];
    v.x = fmaxf(v.x, 0.f); v.y = fmaxf(v.y, 0.f);
    v.z = fmaxf(v.z, 0.f); v.w = fmaxf(v.w, 0.f);
    p[i] = v;
}

extern "C" void kernel_launch(void* const* d_in, const int* in_sizes, int n_in,
                              void* d_out, int out_size, void* d_ws, size_t ws_size,
                              hipStream_t stream) {
    const float* h    = (const float*)d_in[0];
    const float* coup = (const float*)d_in[1];
    const float* W1   = (const float*)d_in[2];
    const float* b1   = (const float*)d_in[3];
    const float* W2   = (const float*)d_in[4];
    const float* b2   = (const float*)d_in[5];
    // d_in[6..9] = Wq, bq, Wk, bk: unused — softmax over a size-1 axis is 1.0
    const int* senders   = (const int*)d_in[10];
    const int* receivers = (const int*)d_in[11];
    float* out = (float*)d_out;

    if (ws_size >= (size_t)WS_NEED) {
        char* ws = (char*)d_ws;
        int*  row_start = (int*)(ws + OFF_ROW);
        int*  counts    = (int*)(ws + OFF_CNT);
        int2* sorted_sc = (int2*)(ws + OFF_SC);
        __hip_bfloat16* Atab = (__hip_bfloat16*)(ws + OFF_A);
        __hip_bfloat16* Btab = (__hip_bfloat16*)(ws + OFF_B);

        hipMemsetAsync(counts, 0, NN * sizeof(int), stream);
        hist_kernel<<<NE / 256, 256, 0, stream>>>(receivers, counts);
        scan_kernel<<<1, 1024, 0, stream>>>(counts, row_start);
        hipMemsetAsync(counts, 0, NN * sizeof(int), stream);   // reuse as cursor
        scatter_kernel<<<NE / 256, 256, 0, stream>>>(
            senders, receivers, coup, row_start, counts, sorted_sc);
        precompute_kernel<<<NN * JB / 256, 256, 0, stream>>>(h, W1, b1, Atab, Btab);
        node_gather_kernel<<<NN / 4, 256, 0, stream>>>(
            row_start, sorted_sc,
            (const unsigned int*)Atab, (const unsigned int*)Btab,
            W1, W2, b2, out);
    } else {
        hipMemsetAsync(d_out, 0, (size_t)out_size * sizeof(float), stream);
        edge_msg_fallback<<<NE / 256, 256, 0, stream>>>(
            h, coup, W1, b1, W2, b2, senders, receivers, out);
        relu_kernel<<<out_size / 4 / 256, 256, 0, stream>>>(out);
    }
}

// Round 5
// 556.570 us; speedup vs baseline: 6.8688x; 1.2948x over previous
//
#include <hip/hip_runtime.h>
#include <hip/hip_bf16.h>

#define NN 100000
#define NE 1600000
#define NC 800000
#define D  32
#define DE 65
#define JB 72     // bf16 elements per table row (144B, 16B-aligned); 9 uint4
#define KP 33     // LDS k-stride in precompute
#define W1_LD 68  // fallback kernel stride

// ---- ws byte offsets (16B-aligned) ----
#define OFF_ROW 0u                  // int[NN+1]    row_start
#define OFF_CNT 400016u             // int[NN]      counts / cursor
#define OFF_SC  800016u             // int2[NE]     (sender, coupling-bits), receiver-grouped
#define OFF_A   13600016u           // bf16[NN*JB]  A table (b1 folded)
#define OFF_B   28000016u           // bf16[NN*JB]  B table
#define WS_NEED 42400016u

typedef __attribute__((ext_vector_type(8))) short short8;
typedef __attribute__((ext_vector_type(4))) float f32x4;

__device__ __forceinline__ float selu_f(float x) {
    // branch-free: x>0 -> scale*x ; x<0 -> scale*alpha*(exp(x)-1)
    float p = fmaxf(x, 0.f);
    float m = fminf(x, 0.f);
    return fmaf(1.7580993408473766f, __expf(m) - 1.f, 1.0507009873554805f * p);
}

__device__ __forceinline__ float2 bf2(unsigned int u) {
    // two packed bf16 -> two floats (element 0 in low 16 bits)
    return make_float2(__uint_as_float(u << 16), __uint_as_float(u & 0xffff0000u));
}

__device__ __forceinline__ short f2bf(float x) {
    union { __hip_bfloat16 h; short s; } u;
    u.h = __float2bfloat16(x);
    return u.s;
}

// ---------------- CSR build ----------------
__global__ __launch_bounds__(256) void hist_kernel(
    const int4* __restrict__ recv4, int* __restrict__ counts)
{
    const int i4 = blockIdx.x * 256 + threadIdx.x;
    if (i4 >= NE / 4) return;
    int4 r = recv4[i4];
    atomicAdd(&counts[r.x], 1);
    atomicAdd(&counts[r.y], 1);
    atomicAdd(&counts[r.z], 1);
    atomicAdd(&counts[r.w], 1);
}

__global__ __launch_bounds__(1024) void scan_kernel(
    const int* __restrict__ counts, int* __restrict__ row_start)
{
    __shared__ int ssum[1024];
    const int tid = threadIdx.x;
    const int chunk = (NN + 1023) / 1024;           // 98
    const int lo = tid * chunk;
    const int hi = lo + chunk < NN ? lo + chunk : NN;
    int s = 0;
    for (int i = lo; i < hi; ++i) s += counts[i];
    ssum[tid] = s;
    __syncthreads();
    for (int off = 1; off < 1024; off <<= 1) {      // inclusive scan
        int v = (tid >= off) ? ssum[tid - off] : 0;
        __syncthreads();
        ssum[tid] += v;
        __syncthreads();
    }
    int off = ssum[tid] - s;                        // exclusive base
    for (int i = lo; i < hi; ++i) { row_start[i] = off; off += counts[i]; }
    if (tid == 0) row_start[NN] = ssum[1023];
}

__global__ __launch_bounds__(256) void scatter_kernel(
    const int4* __restrict__ send4, const int4* __restrict__ recv4,
    const float4* __restrict__ coup4,
    const int* __restrict__ row_start, int* __restrict__ cursor,
    int2* __restrict__ sorted_sc)
{
    const int i4 = blockIdx.x * 256 + threadIdx.x;
    if (i4 >= NE / 4) return;
    const int4 r = recv4[i4];
    const int4 s = send4[i4];
    const int e = i4 * 4;
    const float4 c = coup4[e < NC ? i4 : i4 - NC / 4];   // NC % 4 == 0: no straddle
    int pos;
    pos = atomicAdd(&cursor[r.x], 1); sorted_sc[row_start[r.x] + pos] = make_int2(s.x, __float_as_int(c.x));
    pos = atomicAdd(&cursor[r.y], 1); sorted_sc[row_start[r.y] + pos] = make_int2(s.y, __float_as_int(c.y));
    pos = atomicAdd(&cursor[r.z], 1); sorted_sc[row_start[r.z] + pos] = make_int2(s.z, __float_as_int(c.z));
    pos = atomicAdd(&cursor[r.w], 1); sorted_sc[row_start[r.w] + pos] = make_int2(s.w, __float_as_int(c.w));
}

// ---------------- per-node layer-1 halves, bf16 ----------------
// A[n][j] = b1[j] + sum_k h[n][k]*W1[k][j]      (k in [0,32))
// B[n][j] =          sum_k h[n][k]*W1[32+k][j]
__global__ __launch_bounds__(256) void precompute_kernel(
    const float* __restrict__ h, const float* __restrict__ W1,
    const float* __restrict__ b1,
    __hip_bfloat16* __restrict__ A, __hip_bfloat16* __restrict__ B)
{
    __shared__ float sWA[JB * KP];
    __shared__ float sWB[JB * KP];
    __shared__ float sb1[JB];
    for (int i = threadIdx.x; i < JB * 32; i += 256) {
        int j = i >> 5, k = i & 31;
        sWA[j * KP + k] = (j < DE) ? W1[k * DE + j] : 0.f;
        sWB[j * KP + k] = (j < DE) ? W1[(k + 32) * DE + j] : 0.f;
    }
    if (threadIdx.x < JB) sb1[threadIdx.x] = (threadIdx.x < DE) ? b1[threadIdx.x] : 0.f;
    __syncthreads();

    const int idx = blockIdx.x * 256 + threadIdx.x;   // grid covers NN*JB exactly
    const int n = idx / JB;
    const int j = idx - n * JB;
    const float4* hr = reinterpret_cast<const float4*>(h + (size_t)n * D);
    const float* wa = &sWA[j * KP];
    const float* wb = &sWB[j * KP];
    float a = sb1[j], b = 0.f;
    #pragma unroll
    for (int kk = 0; kk < 8; ++kk) {
        float4 hv = hr[kk];
        a = fmaf(hv.x, wa[4*kk+0], a); a = fmaf(hv.y, wa[4*kk+1], a);
        a = fmaf(hv.z, wa[4*kk+2], a); a = fmaf(hv.w, wa[4*kk+3], a);
        b = fmaf(hv.x, wb[4*kk+0], b); b = fmaf(hv.y, wb[4*kk+1], b);
        b = fmaf(hv.z, wb[4*kk+2], b); b = fmaf(hv.w, wb[4*kk+3], b);
    }
    A[idx] = __float2bfloat16(j < DE ? a : 0.f);
    B[idx] = __float2bfloat16(j < DE ? b : 0.f);
}

// ---------------- node-centric MFMA edge kernel: one wave per receiver ----------------
// Per 16-edge tile: lane (er=lane&15, g=lane>>4) computes 8 hidden units
// j = 32c + 8g + i for edge er, packs bf16 A-frag; W2 lives in register B-frags.
// A/B use the same (g,i)->unit convention so the HW k-mapping cancels.
// C/D: col=lane&15, row=(lane>>4)*4+reg (HW-verified layout).
__global__ __launch_bounds__(256) void node_mfma_kernel(
    const int* __restrict__ row_start,
    const int2* __restrict__ sorted_sc,
    const uint4* __restrict__ Au4,
    const uint4* __restrict__ Bu4,
    const float* __restrict__ W1,
    const float* __restrict__ W2,
    const float* __restrict__ b2,
    float* __restrict__ out)
{
    const int lane = threadIdx.x & 63;
    const int wid  = threadIdx.x >> 6;
    const int n    = blockIdx.x * 4 + wid;   // grid covers NN exactly
    const int g    = lane >> 4;              // k-octet group
    const int er   = lane & 15;              // edge slot (A row) / output col (C)

    // coupling column of W1, per-lane slices
    float w1c0[8], w1c1[8];
    #pragma unroll
    for (int i = 0; i < 8; ++i) {
        w1c0[i] = W1[64 * DE + 8 * g + i];
        w1c1[i] = W1[64 * DE + 32 + 8 * g + i];
    }
    const float w1c64 = W1[64 * DE + 64];

    // W2 B-fragments: WB[chunk][colhalf][i] = W2[32c+8g+i][16hf+er]
    short8 WB[2][2];
    #pragma unroll
    for (int c = 0; c < 2; ++c)
        #pragma unroll
        for (int hf = 0; hf < 2; ++hf)
            #pragma unroll
            for (int i = 0; i < 8; ++i)
                WB[c][hf][i] = f2bf(W2[(32 * c + 8 * g + i) * D + 16 * hf + er]);
    short8 WB64[2];
    #pragma unroll
    for (int hf = 0; hf < 2; ++hf) {
        #pragma unroll
        for (int i = 0; i < 8; ++i) WB64[hf][i] = (short)0;
        WB64[hf][0] = (g == 0) ? f2bf(W2[64 * D + 16 * hf + er]) : (short)0;
    }
    const float b2lo = b2[er];
    const float b2hi = b2[16 + er];

    // per-node A-row slices (b1 folded), unpacked to f32 once
    const uint4 a0 = Au4[(size_t)n * 9 + g];
    const uint4 a1 = Au4[(size_t)n * 9 + 4 + g];
    float af0[8], af1[8];
    {
        float2 t;
        t = bf2(a0.x); af0[0] = t.x; af0[1] = t.y;
        t = bf2(a0.y); af0[2] = t.x; af0[3] = t.y;
        t = bf2(a0.z); af0[4] = t.x; af0[5] = t.y;
        t = bf2(a0.w); af0[6] = t.x; af0[7] = t.y;
        t = bf2(a1.x); af1[0] = t.x; af1[1] = t.y;
        t = bf2(a1.y); af1[2] = t.x; af1[3] = t.y;
        t = bf2(a1.z); af1[4] = t.x; af1[5] = t.y;
        t = bf2(a1.w); af1[6] = t.x; af1[7] = t.y;
    }
    const float af64 = bf2(reinterpret_cast<const unsigned*>(Au4)[(size_t)n * 36 + 32]).x;

    const int rbeg = row_start[n];
    const int rend = row_start[n + 1];
    float acc0 = 0.f, acc1 = 0.f;

    for (int tb = rbeg; tb < rend; tb += 16) {
        const int valid = (rend - tb < 16) ? rend - tb : 16;
        const int2 sc = sorted_sc[tb + (er < valid ? er : 0)];
        const int   se = sc.x;
        const float ce = __int_as_float(sc.y);

        const uint4 bv0 = Bu4[(size_t)se * 9 + g];
        const uint4 bv1 = Bu4[(size_t)se * 9 + 4 + g];
        const unsigned b64u = reinterpret_cast<const unsigned*>(Bu4)[(size_t)se * 36 + 32];

        short8 A0, A1, A2;
        {
            float2 t;
            t = bf2(bv0.x); A0[0] = f2bf(selu_f(fmaf(ce, w1c0[0], af0[0] + t.x)));
                            A0[1] = f2bf(selu_f(fmaf(ce, w1c0[1], af0[1] + t.y)));
            t = bf2(bv0.y); A0[2] = f2bf(selu_f(fmaf(ce, w1c0[2], af0[2] + t.x)));
                            A0[3] = f2bf(selu_f(fmaf(ce, w1c0[3], af0[3] + t.y)));
            t = bf2(bv0.z); A0[4] = f2bf(selu_f(fmaf(ce, w1c0[4], af0[4] + t.x)));
                            A0[5] = f2bf(selu_f(fmaf(ce, w1c0[5], af0[5] + t.y)));
            t = bf2(bv0.w); A0[6] = f2bf(selu_f(fmaf(ce, w1c0[6], af0[6] + t.x)));
                            A0[7] = f2bf(selu_f(fmaf(ce, w1c0[7], af0[7] + t.y)));
            t = bf2(bv1.x); A1[0] = f2bf(selu_f(fmaf(ce, w1c1[0], af1[0] + t.x)));
                            A1[1] = f2bf(selu_f(fmaf(ce, w1c1[1], af1[1] + t.y)));
            t = bf2(bv1.y); A1[2] = f2bf(selu_f(fmaf(ce, w1c1[2], af1[2] + t.x)));
                            A1[3] = f2bf(selu_f(fmaf(ce, w1c1[3], af1[3] + t.y)));
            t = bf2(bv1.z); A1[4] = f2bf(selu_f(fmaf(ce, w1c1[4], af1[4] + t.x)));
                            A1[5] = f2bf(selu_f(fmaf(ce, w1c1[5], af1[5] + t.y)));
            t = bf2(bv1.w); A1[6] = f2bf(selu_f(fmaf(ce, w1c1[6], af1[6] + t.x)));
                            A1[7] = f2bf(selu_f(fmaf(ce, w1c1[7], af1[7] + t.y)));
        }
        const float h64 = selu_f(fmaf(ce, w1c64, af64 + bf2(b64u).x));
        #pragma unroll
        for (int i = 0; i < 8; ++i) A2[i] = (short)0;
        A2[0] = (g == 0) ? f2bf(h64) : (short)0;

        f32x4 Clo = {0.f, 0.f, 0.f, 0.f};
        f32x4 Chi = {0.f, 0.f, 0.f, 0.f};
        Clo = __builtin_amdgcn_mfma_f32_16x16x32_bf16(A0, WB[0][0], Clo, 0, 0, 0);
        Clo = __builtin_amdgcn_mfma_f32_16x16x32_bf16(A1, WB[1][0], Clo, 0, 0, 0);
        Clo = __builtin_amdgcn_mfma_f32_16x16x32_bf16(A2, WB64[0],  Clo, 0, 0, 0);
        Chi = __builtin_amdgcn_mfma_f32_16x16x32_bf16(A0, WB[0][1], Chi, 0, 0, 0);
        Chi = __builtin_amdgcn_mfma_f32_16x16x32_bf16(A1, WB[1][1], Chi, 0, 0, 0);
        Chi = __builtin_amdgcn_mfma_f32_16x16x32_bf16(A2, WB64[1],  Chi, 0, 0, 0);

        // epilogue: bias + outer selu per edge-row, mask padded rows, sum rows
        float plo = 0.f, phi = 0.f;
        #pragma unroll
        for (int r = 0; r < 4; ++r) {
            const bool on = (4 * g + r) < valid;
            plo += on ? selu_f(Clo[r] + b2lo) : 0.f;
            phi += on ? selu_f(Chi[r] + b2hi) : 0.f;
        }
        plo += __shfl_xor(plo, 16); plo += __shfl_xor(plo, 32);
        phi += __shfl_xor(phi, 16); phi += __shfl_xor(phi, 32);
        acc0 += plo; acc1 += phi;
    }

    if (lane < 16) {
        out[(size_t)n * D + er]      = fmaxf(acc0, 0.f);
        out[(size_t)n * D + 16 + er] = fmaxf(acc1, 0.f);
    }
}

// ---------------- fallback (ws too small): monolithic round-1 kernel ----------
__global__ __launch_bounds__(256) void edge_msg_fallback(
    const float* __restrict__ h, const float* __restrict__ coup,
    const float* __restrict__ W1, const float* __restrict__ b1,
    const float* __restrict__ W2, const float* __restrict__ b2,
    const int* __restrict__ senders, const int* __restrict__ receivers,
    float* __restrict__ out)
{
    __shared__ float sW1t[DE * W1_LD];
    __shared__ float sW2[DE * D];
    __shared__ float sb1[DE];
    __shared__ float sb2[D];
    for (int i = threadIdx.x; i < DE * DE; i += 256) {
        int k = i / DE, j = i - k * DE;
        sW1t[j * W1_LD + k] = W1[i];
    }
    for (int i = threadIdx.x; i < DE * D; i += 256) sW2[i] = W2[i];
    if (threadIdx.x < DE) sb1[threadIdx.x] = b1[threadIdx.x];
    if (threadIdx.x >= 128 && threadIdx.x < 128 + D) sb2[threadIdx.x - 128] = b2[threadIdx.x - 128];
    __syncthreads();
    const int e = blockIdx.x * 256 + threadIdx.x;
    const int s = senders[e];
    const int r = receivers[e];
    float edgef[DE];
    const float4* hr = reinterpret_cast<const float4*>(h + (size_t)r * D);
    const float4* hs = reinterpret_cast<const float4*>(h + (size_t)s * D);
    #pragma unroll
    for (int i = 0; i < 8; ++i) {
        float4 v = hr[i];
        edgef[4*i] = v.x; edgef[4*i+1] = v.y; edgef[4*i+2] = v.z; edgef[4*i+3] = v.w;
    }
    #pragma unroll
    for (int i = 0; i < 8; ++i) {
        float4 v = hs[i];
        edgef[D+4*i] = v.x; edgef[D+4*i+1] = v.y; edgef[D+4*i+2] = v.z; edgef[D+4*i+3] = v.w;
    }
    edgef[2*D] = coup[e < NC ? e : e - NC];
    float acc[D];
    #pragma unroll
    for (int d2 = 0; d2 < D; ++d2) acc[d2] = sb2[d2];
    for (int j = 0; j < DE; ++j) {
        const float* wrow = &sW1t[j * W1_LD];
        float p0 = 0.f, p1 = 0.f, p2 = 0.f, p3 = 0.f;
        #pragma unroll
        for (int k = 0; k < 64; k += 4) {
            p0 = fmaf(edgef[k], wrow[k], p0);
            p1 = fmaf(edgef[k+1], wrow[k+1], p1);
            p2 = fmaf(edgef[k+2], wrow[k+2], p2);
            p3 = fmaf(edgef[k+3], wrow[k+3], p3);
        }
        float hj = selu_f(sb1[j] + fmaf(edgef[64], wrow[64], (p0+p1)+(p2+p3)));
        const float* w2row = &sW2[j * D];
        #pragma unroll
        for (int d2 = 0; d2 < D; ++d2) acc[d2] = fmaf(hj, w2row[d2], acc[d2]);
    }
    float* op = out + (size_t)r * D;
    #pragma unroll
    for (int d2 = 0; d2 < D; ++d2) unsafeAtomicAdd(op + d2, selu_f(acc[d2]));
}

__global__ __launch_bounds__(256) void relu_kernel(float* __restrict__ out) {
    const int i = blockIdx.x * 256 + threadIdx.x;
    float4* p = reinterpret_cast<float4*>(out);
    float4 v = p[i];
    v.x = fmaxf(v.x, 0.f); v.y = fmaxf(v.y, 0.f);
    v.z = fmaxf(v.z, 0.f); v.w = fmaxf(v.w, 0.f);
    p[i] = v;
}

extern "C" void kernel_launch(void* const* d_in, const int* in_sizes, int n_in,
                              void* d_out, int out_size, void* d_ws, size_t ws_size,
                              hipStream_t stream) {
    const float* h    = (const float*)d_in[0];
    const float* coup = (const float*)d_in[1];
    const float* W1   = (const float*)d_in[2];
    const float* b1   = (const float*)d_in[3];
    const float* W2   = (const float*)d_in[4];
    const float* b2   = (const float*)d_in[5];
    // d_in[6..9] = Wq, bq, Wk, bk: unused — softmax over a size-1 axis is 1.0
    const int* senders   = (const int*)d_in[10];
    const int* receivers = (const int*)d_in[11];
    float* out = (float*)d_out;

    if (ws_size >= (size_t)WS_NEED) {
        char* ws = (char*)d_ws;
        int*  row_start = (int*)(ws + OFF_ROW);
        int*  counts    = (int*)(ws + OFF_CNT);
        int2* sorted_sc = (int2*)(ws + OFF_SC);
        __hip_bfloat16* Atab = (__hip_bfloat16*)(ws + OFF_A);
        __hip_bfloat16* Btab = (__hip_bfloat16*)(ws + OFF_B);

        hipMemsetAsync(counts, 0, NN * sizeof(int), stream);
        hist_kernel<<<(NE / 4 + 255) / 256, 256, 0, stream>>>(
            (const int4*)receivers, counts);
        scan_kernel<<<1, 1024, 0, stream>>>(counts, row_start);
        hipMemsetAsync(counts, 0, NN * sizeof(int), stream);   // reuse as cursor
        scatter_kernel<<<(NE / 4 + 255) / 256, 256, 0, stream>>>(
            (const int4*)senders, (const int4*)receivers, (const float4*)coup,
            row_start, counts, sorted_sc);
        precompute_kernel<<<NN * JB / 256, 256, 0, stream>>>(h, W1, b1, Atab, Btab);
        node_mfma_kernel<<<NN / 4, 256, 0, stream>>>(
            row_start, sorted_sc,
            (const uint4*)Atab, (const uint4*)Btab,
            W1, W2, b2, out);
    } else {
        hipMemsetAsync(d_out, 0, (size_t)out_size * sizeof(float), stream);
        edge_msg_fallback<<<NE / 256, 256, 0, stream>>>(
            h, coup, W1, b1, W2, b2, senders, receivers, out);
        relu_kernel<<<out_size / 4 / 256, 256, 0, stream>>>(out);
    }
}

// Round 6
// 405.861 us; speedup vs baseline: 9.4194x; 1.3713x over previous
//
#include <hip/hip_runtime.h>
#include <hip/hip_bf16.h>

#define NN 100000
#define NE 1600000
#define NC 800000
#define D  32
#define DE 65
#define JB 72     // bf16 elements per table row (144B, 16B-aligned); 9 uint4
#define KP 33     // LDS k-stride in precompute
#define W1_LD 68  // fallback kernel stride
#define NBLK 391  // ceil(NN/256) scan blocks

// ---- ws byte offsets (16B-aligned) ----
#define OFF_ROW 0u                  // int[NN+1]    row_start
#define OFF_CNT 400016u             // int[NN]      counts / cursor
#define OFF_SC  800016u             // int2[NE]     (sender, coupling-bits), receiver-grouped
#define OFF_A   13600016u           // bf16[NN*JB]  A table (b1 folded); also scan blocksum scratch
#define OFF_B   28000016u           // bf16[NN*JB]  B table
#define WS_NEED 42400016u

typedef __attribute__((ext_vector_type(8))) short short8;
typedef __attribute__((ext_vector_type(4))) float f32x4;

__device__ __forceinline__ float selu_f(float x) {
    // branch-free: x>0 -> scale*x ; x<0 -> scale*alpha*(exp(x)-1)
    float p = fmaxf(x, 0.f);
    float m = fminf(x, 0.f);
    return fmaf(1.7580993408473766f, __expf(m) - 1.f, 1.0507009873554805f * p);
}

__device__ __forceinline__ float2 bf2(unsigned int u) {
    // two packed bf16 -> two floats (element 0 in low 16 bits)
    return make_float2(__uint_as_float(u << 16), __uint_as_float(u & 0xffff0000u));
}

__device__ __forceinline__ short f2bf(float x) {
    union { __hip_bfloat16 h; short s; } u;
    u.h = __float2bfloat16(x);
    return u.s;
}

// ---------------- CSR build ----------------
__global__ __launch_bounds__(256) void hist_kernel(
    const int4* __restrict__ recv4, int* __restrict__ counts)
{
    const int i4 = blockIdx.x * 256 + threadIdx.x;
    if (i4 >= NE / 4) return;
    int4 r = recv4[i4];
    atomicAdd(&counts[r.x], 1);
    atomicAdd(&counts[r.y], 1);
    atomicAdd(&counts[r.z], 1);
    atomicAdd(&counts[r.w], 1);
}

// block-local exclusive scan of counts -> row_start; per-block totals -> blocksum
__global__ __launch_bounds__(256) void scan1_kernel(
    const int* __restrict__ counts, int* __restrict__ row_start,
    int* __restrict__ blocksum)
{
    const int gid = blockIdx.x * 256 + threadIdx.x;
    const int v = (gid < NN) ? counts[gid] : 0;
    const int lane = threadIdx.x & 63;
    int incl = v;
    #pragma unroll
    for (int off = 1; off < 64; off <<= 1) {
        int t = __shfl_up(incl, off);
        if (lane >= off) incl += t;
    }
    __shared__ int wsum[4];
    if (lane == 63) wsum[threadIdx.x >> 6] = incl;
    __syncthreads();
    const int w = threadIdx.x >> 6;
    int base = 0;
    #pragma unroll
    for (int i = 0; i < 4; ++i) base += (i < w) ? wsum[i] : 0;
    incl += base;
    if (gid < NN) row_start[gid] = incl - v;         // local exclusive
    if (threadIdx.x == 255) blocksum[blockIdx.x] = incl;
}

// single-block exclusive scan of the NBLK block sums
__global__ __launch_bounds__(512) void scan2_kernel(int* __restrict__ blocksum)
{
    const int tid = threadIdx.x;
    const int v = (tid < NBLK) ? blocksum[tid] : 0;
    const int lane = tid & 63;
    int incl = v;
    #pragma unroll
    for (int off = 1; off < 64; off <<= 1) {
        int t = __shfl_up(incl, off);
        if (lane >= off) incl += t;
    }
    __shared__ int wsum[8];
    if (lane == 63) wsum[tid >> 6] = incl;
    __syncthreads();
    const int w = tid >> 6;
    int base = 0;
    #pragma unroll
    for (int i = 0; i < 8; ++i) base += (i < w) ? wsum[i] : 0;
    incl += base;
    if (tid < NBLK) blocksum[tid] = incl - v;        // exclusive block offset
}

__global__ __launch_bounds__(256) void scan3_kernel(
    int* __restrict__ row_start, const int* __restrict__ blocksum)
{
    const int gid = blockIdx.x * 256 + threadIdx.x;
    if (gid < NN) row_start[gid] += blocksum[blockIdx.x];
    if (gid == 0) row_start[NN] = NE;                // total edge count is constant
}

__global__ __launch_bounds__(256) void scatter_kernel(
    const int4* __restrict__ send4, const int4* __restrict__ recv4,
    const float4* __restrict__ coup4,
    const int* __restrict__ row_start, int* __restrict__ cursor,
    int2* __restrict__ sorted_sc)
{
    const int i4 = blockIdx.x * 256 + threadIdx.x;
    if (i4 >= NE / 4) return;
    const int4 r = recv4[i4];
    const int4 s = send4[i4];
    const int e = i4 * 4;
    const float4 c = coup4[e < NC ? i4 : i4 - NC / 4];   // NC % 4 == 0: no straddle
    int pos;
    pos = atomicAdd(&cursor[r.x], 1); sorted_sc[row_start[r.x] + pos] = make_int2(s.x, __float_as_int(c.x));
    pos = atomicAdd(&cursor[r.y], 1); sorted_sc[row_start[r.y] + pos] = make_int2(s.y, __float_as_int(c.y));
    pos = atomicAdd(&cursor[r.z], 1); sorted_sc[row_start[r.z] + pos] = make_int2(s.z, __float_as_int(c.z));
    pos = atomicAdd(&cursor[r.w], 1); sorted_sc[row_start[r.w] + pos] = make_int2(s.w, __float_as_int(c.w));
}

// ---------------- per-node layer-1 halves, bf16 ----------------
// A[n][j] = b1[j] + sum_k h[n][k]*W1[k][j]      (k in [0,32))
// B[n][j] =          sum_k h[n][k]*W1[32+k][j]
__global__ __launch_bounds__(256) void precompute_kernel(
    const float* __restrict__ h, const float* __restrict__ W1,
    const float* __restrict__ b1,
    __hip_bfloat16* __restrict__ A, __hip_bfloat16* __restrict__ B)
{
    __shared__ float sWA[JB * KP];
    __shared__ float sWB[JB * KP];
    __shared__ float sb1[JB];
    for (int i = threadIdx.x; i < JB * 32; i += 256) {
        int j = i >> 5, k = i & 31;
        sWA[j * KP + k] = (j < DE) ? W1[k * DE + j] : 0.f;
        sWB[j * KP + k] = (j < DE) ? W1[(k + 32) * DE + j] : 0.f;
    }
    if (threadIdx.x < JB) sb1[threadIdx.x] = (threadIdx.x < DE) ? b1[threadIdx.x] : 0.f;
    __syncthreads();

    const int idx = blockIdx.x * 256 + threadIdx.x;   // grid covers NN*JB exactly
    const int n = idx / JB;
    const int j = idx - n * JB;
    const float4* hr = reinterpret_cast<const float4*>(h + (size_t)n * D);
    const float* wa = &sWA[j * KP];
    const float* wb = &sWB[j * KP];
    float a = sb1[j], b = 0.f;
    #pragma unroll
    for (int kk = 0; kk < 8; ++kk) {
        float4 hv = hr[kk];
        a = fmaf(hv.x, wa[4*kk+0], a); a = fmaf(hv.y, wa[4*kk+1], a);
        a = fmaf(hv.z, wa[4*kk+2], a); a = fmaf(hv.w, wa[4*kk+3], a);
        b = fmaf(hv.x, wb[4*kk+0], b); b = fmaf(hv.y, wb[4*kk+1], b);
        b = fmaf(hv.z, wb[4*kk+2], b); b = fmaf(hv.w, wb[4*kk+3], b);
    }
    A[idx] = __float2bfloat16(j < DE ? a : 0.f);
    B[idx] = __float2bfloat16(j < DE ? b : 0.f);
}

// ---------------- node-centric MFMA edge kernel: one wave per receiver ----------------
// Per 16-edge tile: lane (er=lane&15, g=lane>>4) computes 8 hidden units
// j = 32c + 8g + i for edge er, packs bf16 A-frag; W2 lives in register B-frags.
// A/B use the same (g,i)->unit convention so the HW k-mapping cancels.
// C/D: col=lane&15, row=(lane>>4)*4+reg (HW-verified layout).
__global__ __launch_bounds__(256) void node_mfma_kernel(
    const int* __restrict__ row_start,
    const int2* __restrict__ sorted_sc,
    const uint4* __restrict__ Au4,
    const uint4* __restrict__ Bu4,
    const float* __restrict__ W1,
    const float* __restrict__ W2,
    const float* __restrict__ b2,
    float* __restrict__ out)
{
    const int lane = threadIdx.x & 63;
    const int wid  = threadIdx.x >> 6;
    const int n    = blockIdx.x * 4 + wid;   // grid covers NN exactly
    const int g    = lane >> 4;              // k-octet group
    const int er   = lane & 15;              // edge slot (A row) / output col (C)

    // coupling column of W1, per-lane slices
    float w1c0[8], w1c1[8];
    #pragma unroll
    for (int i = 0; i < 8; ++i) {
        w1c0[i] = W1[64 * DE + 8 * g + i];
        w1c1[i] = W1[64 * DE + 32 + 8 * g + i];
    }
    const float w1c64 = W1[64 * DE + 64];

    // W2 B-fragments: WB[chunk][colhalf][i] = W2[32c+8g+i][16hf+er]
    short8 WB[2][2];
    #pragma unroll
    for (int c = 0; c < 2; ++c)
        #pragma unroll
        for (int hf = 0; hf < 2; ++hf)
            #pragma unroll
            for (int i = 0; i < 8; ++i)
                WB[c][hf][i] = f2bf(W2[(32 * c + 8 * g + i) * D + 16 * hf + er]);
    short8 WB64[2];
    #pragma unroll
    for (int hf = 0; hf < 2; ++hf) {
        #pragma unroll
        for (int i = 0; i < 8; ++i) WB64[hf][i] = (short)0;
        WB64[hf][0] = (g == 0) ? f2bf(W2[64 * D + 16 * hf + er]) : (short)0;
    }
    const float b2lo = b2[er];
    const float b2hi = b2[16 + er];

    // per-node A-row slices (b1 folded), unpacked to f32 once
    const uint4 a0 = Au4[(size_t)n * 9 + g];
    const uint4 a1 = Au4[(size_t)n * 9 + 4 + g];
    float af0[8], af1[8];
    {
        float2 t;
        t = bf2(a0.x); af0[0] = t.x; af0[1] = t.y;
        t = bf2(a0.y); af0[2] = t.x; af0[3] = t.y;
        t = bf2(a0.z); af0[4] = t.x; af0[5] = t.y;
        t = bf2(a0.w); af0[6] = t.x; af0[7] = t.y;
        t = bf2(a1.x); af1[0] = t.x; af1[1] = t.y;
        t = bf2(a1.y); af1[2] = t.x; af1[3] = t.y;
        t = bf2(a1.z); af1[4] = t.x; af1[5] = t.y;
        t = bf2(a1.w); af1[6] = t.x; af1[7] = t.y;
    }
    const float af64 = bf2(reinterpret_cast<const unsigned*>(Au4)[(size_t)n * 36 + 32]).x;

    const int rbeg = row_start[n];
    const int rend = row_start[n + 1];
    float acc0 = 0.f, acc1 = 0.f;

    for (int tb = rbeg; tb < rend; tb += 16) {
        const int valid = (rend - tb < 16) ? rend - tb : 16;
        const int2 sc = sorted_sc[tb + (er < valid ? er : 0)];
        const int   se = sc.x;
        const float ce = __int_as_float(sc.y);

        const uint4 bv0 = Bu4[(size_t)se * 9 + g];
        const uint4 bv1 = Bu4[(size_t)se * 9 + 4 + g];
        const unsigned b64u = reinterpret_cast<const unsigned*>(Bu4)[(size_t)se * 36 + 32];

        short8 A0, A1, A2;
        {
            float2 t;
            t = bf2(bv0.x); A0[0] = f2bf(selu_f(fmaf(ce, w1c0[0], af0[0] + t.x)));
                            A0[1] = f2bf(selu_f(fmaf(ce, w1c0[1], af0[1] + t.y)));
            t = bf2(bv0.y); A0[2] = f2bf(selu_f(fmaf(ce, w1c0[2], af0[2] + t.x)));
                            A0[3] = f2bf(selu_f(fmaf(ce, w1c0[3], af0[3] + t.y)));
            t = bf2(bv0.z); A0[4] = f2bf(selu_f(fmaf(ce, w1c0[4], af0[4] + t.x)));
                            A0[5] = f2bf(selu_f(fmaf(ce, w1c0[5], af0[5] + t.y)));
            t = bf2(bv0.w); A0[6] = f2bf(selu_f(fmaf(ce, w1c0[6], af0[6] + t.x)));
                            A0[7] = f2bf(selu_f(fmaf(ce, w1c0[7], af0[7] + t.y)));
            t = bf2(bv1.x); A1[0] = f2bf(selu_f(fmaf(ce, w1c1[0], af1[0] + t.x)));
                            A1[1] = f2bf(selu_f(fmaf(ce, w1c1[1], af1[1] + t.y)));
            t = bf2(bv1.y); A1[2] = f2bf(selu_f(fmaf(ce, w1c1[2], af1[2] + t.x)));
                            A1[3] = f2bf(selu_f(fmaf(ce, w1c1[3], af1[3] + t.y)));
            t = bf2(bv1.z); A1[4] = f2bf(selu_f(fmaf(ce, w1c1[4], af1[4] + t.x)));
                            A1[5] = f2bf(selu_f(fmaf(ce, w1c1[5], af1[5] + t.y)));
            t = bf2(bv1.w); A1[6] = f2bf(selu_f(fmaf(ce, w1c1[6], af1[6] + t.x)));
                            A1[7] = f2bf(selu_f(fmaf(ce, w1c1[7], af1[7] + t.y)));
        }
        const float h64 = selu_f(fmaf(ce, w1c64, af64 + bf2(b64u).x));
        #pragma unroll
        for (int i = 0; i < 8; ++i) A2[i] = (short)0;
        A2[0] = (g == 0) ? f2bf(h64) : (short)0;

        f32x4 Clo = {0.f, 0.f, 0.f, 0.f};
        f32x4 Chi = {0.f, 0.f, 0.f, 0.f};
        Clo = __builtin_amdgcn_mfma_f32_16x16x32_bf16(A0, WB[0][0], Clo, 0, 0, 0);
        Clo = __builtin_amdgcn_mfma_f32_16x16x32_bf16(A1, WB[1][0], Clo, 0, 0, 0);
        Clo = __builtin_amdgcn_mfma_f32_16x16x32_bf16(A2, WB64[0],  Clo, 0, 0, 0);
        Chi = __builtin_amdgcn_mfma_f32_16x16x32_bf16(A0, WB[0][1], Chi, 0, 0, 0);
        Chi = __builtin_amdgcn_mfma_f32_16x16x32_bf16(A1, WB[1][1], Chi, 0, 0, 0);
        Chi = __builtin_amdgcn_mfma_f32_16x16x32_bf16(A2, WB64[1],  Chi, 0, 0, 0);

        // epilogue: bias + outer selu per edge-row, mask padded rows, sum rows
        float plo = 0.f, phi = 0.f;
        #pragma unroll
        for (int r = 0; r < 4; ++r) {
            const bool on = (4 * g + r) < valid;
            plo += on ? selu_f(Clo[r] + b2lo) : 0.f;
            phi += on ? selu_f(Chi[r] + b2hi) : 0.f;
        }
        plo += __shfl_xor(plo, 16); plo += __shfl_xor(plo, 32);
        phi += __shfl_xor(phi, 16); phi += __shfl_xor(phi, 32);
        acc0 += plo; acc1 += phi;
    }

    if (lane < 16) {
        out[(size_t)n * D + er]      = fmaxf(acc0, 0.f);
        out[(size_t)n * D + 16 + er] = fmaxf(acc1, 0.f);
    }
}

// ---------------- fallback (ws too small): monolithic round-1 kernel ----------
__global__ __launch_bounds__(256) void edge_msg_fallback(
    const float* __restrict__ h, const float* __restrict__ coup,
    const float* __restrict__ W1, const float* __restrict__ b1,
    const float* __restrict__ W2, const float* __restrict__ b2,
    const int* __restrict__ senders, const int* __restrict__ receivers,
    float* __restrict__ out)
{
    __shared__ float sW1t[DE * W1_LD];
    __shared__ float sW2[DE * D];
    __shared__ float sb1[DE];
    __shared__ float sb2[D];
    for (int i = threadIdx.x; i < DE * DE; i += 256) {
        int k = i / DE, j = i - k * DE;
        sW1t[j * W1_LD + k] = W1[i];
    }
    for (int i = threadIdx.x; i < DE * D; i += 256) sW2[i] = W2[i];
    if (threadIdx.x < DE) sb1[threadIdx.x] = b1[threadIdx.x];
    if (threadIdx.x >= 128 && threadIdx.x < 128 + D) sb2[threadIdx.x - 128] = b2[threadIdx.x - 128];
    __syncthreads();
    const int e = blockIdx.x * 256 + threadIdx.x;
    const int s = senders[e];
    const int r = receivers[e];
    float edgef[DE];
    const float4* hr = reinterpret_cast<const float4*>(h + (size_t)r * D);
    const float4* hs = reinterpret_cast<const float4*>(h + (size_t)s * D);
    #pragma unroll
    for (int i = 0; i < 8; ++i) {
        float4 v = hr[i];
        edgef[4*i] = v.x; edgef[4*i+1] = v.y; edgef[4*i+2] = v.z; edgef[4*i+3] = v.w;
    }
    #pragma unroll
    for (int i = 0; i < 8; ++i) {
        float4 v = hs[i];
        edgef[D+4*i] = v.x; edgef[D+4*i+1] = v.y; edgef[D+4*i+2] = v.z; edgef[D+4*i+3] = v.w;
    }
    edgef[2*D] = coup[e < NC ? e : e - NC];
    float acc[D];
    #pragma unroll
    for (int d2 = 0; d2 < D; ++d2) acc[d2] = sb2[d2];
    for (int j = 0; j < DE; ++j) {
        const float* wrow = &sW1t[j * W1_LD];
        float p0 = 0.f, p1 = 0.f, p2 = 0.f, p3 = 0.f;
        #pragma unroll
        for (int k = 0; k < 64; k += 4) {
            p0 = fmaf(edgef[k], wrow[k], p0);
            p1 = fmaf(edgef[k+1], wrow[k+1], p1);
            p2 = fmaf(edgef[k+2], wrow[k+2], p2);
            p3 = fmaf(edgef[k+3], wrow[k+3], p3);
        }
        float hj = selu_f(sb1[j] + fmaf(edgef[64], wrow[64], (p0+p1)+(p2+p3)));
        const float* w2row = &sW2[j * D];
        #pragma unroll
        for (int d2 = 0; d2 < D; ++d2) acc[d2] = fmaf(hj, w2row[d2], acc[d2]);
    }
    float* op = out + (size_t)r * D;
    #pragma unroll
    for (int d2 = 0; d2 < D; ++d2) unsafeAtomicAdd(op + d2, selu_f(acc[d2]));
}

__global__ __launch_bounds__(256) void relu_kernel(float* __restrict__ out) {
    const int i = blockIdx.x * 256 + threadIdx.x;
    float4* p = reinterpret_cast<float4*>(out);
    float4 v = p[i];
    v.x = fmaxf(v.x, 0.f); v.y = fmaxf(v.y, 0.f);
    v.z = fmaxf(v.z, 0.f); v.w = fmaxf(v.w, 0.f);
    p[i] = v;
}

extern "C" void kernel_launch(void* const* d_in, const int* in_sizes, int n_in,
                              void* d_out, int out_size, void* d_ws, size_t ws_size,
                              hipStream_t stream) {
    const float* h    = (const float*)d_in[0];
    const float* coup = (const float*)d_in[1];
    const float* W1   = (const float*)d_in[2];
    const float* b1   = (const float*)d_in[3];
    const float* W2   = (const float*)d_in[4];
    const float* b2   = (const float*)d_in[5];
    // d_in[6..9] = Wq, bq, Wk, bk: unused — softmax over a size-1 axis is 1.0
    const int* senders   = (const int*)d_in[10];
    const int* receivers = (const int*)d_in[11];
    float* out = (float*)d_out;

    if (ws_size >= (size_t)WS_NEED) {
        char* ws = (char*)d_ws;
        int*  row_start = (int*)(ws + OFF_ROW);
        int*  counts    = (int*)(ws + OFF_CNT);
        int2* sorted_sc = (int2*)(ws + OFF_SC);
        int*  blocksum  = (int*)(ws + OFF_A);   // scratch; overwritten later by precompute
        __hip_bfloat16* Atab = (__hip_bfloat16*)(ws + OFF_A);
        __hip_bfloat16* Btab = (__hip_bfloat16*)(ws + OFF_B);

        hipMemsetAsync(counts, 0, NN * sizeof(int), stream);
        hist_kernel<<<(NE / 4 + 255) / 256, 256, 0, stream>>>(
            (const int4*)receivers, counts);
        scan1_kernel<<<NBLK, 256, 0, stream>>>(counts, row_start, blocksum);
        scan2_kernel<<<1, 512, 0, stream>>>(blocksum);
        scan3_kernel<<<NBLK, 256, 0, stream>>>(row_start, blocksum);
        hipMemsetAsync(counts, 0, NN * sizeof(int), stream);   // reuse as cursor
        scatter_kernel<<<(NE / 4 + 255) / 256, 256, 0, stream>>>(
            (const int4*)senders, (const int4*)receivers, (const float4*)coup,
            row_start, counts, sorted_sc);
        precompute_kernel<<<NN * JB / 256, 256, 0, stream>>>(h, W1, b1, Atab, Btab);
        node_mfma_kernel<<<NN / 4, 256, 0, stream>>>(
            row_start, sorted_sc,
            (const uint4*)Atab, (const uint4*)Btab,
            W1, W2, b2, out);
    } else {
        hipMemsetAsync(d_out, 0, (size_t)out_size * sizeof(float), stream);
        edge_msg_fallback<<<NE / 256, 256, 0, stream>>>(
            h, coup, W1, b1, W2, b2, senders, receivers, out);
        relu_kernel<<<out_size / 4 / 256, 256, 0, stream>>>(out);
    }
}

// Round 8
// 299.047 us; speedup vs baseline: 12.7838x; 1.3572x over previous
//
#include <hip/hip_runtime.h>
#include <hip/hip_bf16.h>

#define NN 100000
#define NE 1600000
#define NC 800000
#define D  32
#define DE 65
#define JB 72     // bf16 elements per table row (144B, 16B-aligned); 9 uint4
#define KP 33     // LDS k-stride in precompute
#define W1_LD 68  // fallback kernel stride
#define NT (NE / 16)   // 100000 full 16-edge tiles (NE % 16 == 0)

// ---- ws byte offsets (16B-aligned) ----
#define OFF_A   0u                  // bf16[NN*JB]  A table (b1 folded)
#define OFF_B   14400000u           // bf16[NN*JB]  B table
#define WS_NEED 28800000u

typedef __attribute__((ext_vector_type(8))) short short8;
typedef __attribute__((ext_vector_type(4))) float f32x4;

__device__ __forceinline__ float selu_f(float x) {
    // branch-free: x>0 -> scale*x ; x<0 -> scale*alpha*(exp(x)-1)
    float p = fmaxf(x, 0.f);
    float m = fminf(x, 0.f);
    return fmaf(1.7580993408473766f, __expf(m) - 1.f, 1.0507009873554805f * p);
}

__device__ __forceinline__ float2 bf2(unsigned int u) {
    // two packed bf16 -> two floats (element 0 in low 16 bits)
    return make_float2(__uint_as_float(u << 16), __uint_as_float(u & 0xffff0000u));
}

__device__ __forceinline__ short f2bf(float x) {
    union { __hip_bfloat16 h; short s; } u;
    u.h = __float2bfloat16(x);
    return u.s;
}

// ---------------- per-node layer-1 halves, bf16 ----------------
// A[n][j] = b1[j] + sum_k h[n][k]*W1[k][j]      (k in [0,32))
// B[n][j] =          sum_k h[n][k]*W1[32+k][j]
__global__ __launch_bounds__(256) void precompute_kernel(
    const float* __restrict__ h, const float* __restrict__ W1,
    const float* __restrict__ b1,
    __hip_bfloat16* __restrict__ A, __hip_bfloat16* __restrict__ B)
{
    __shared__ float sWA[JB * KP];
    __shared__ float sWB[JB * KP];
    __shared__ float sb1[JB];
    for (int i = threadIdx.x; i < JB * 32; i += 256) {
        int j = i >> 5, k = i & 31;
        sWA[j * KP + k] = (j < DE) ? W1[k * DE + j] : 0.f;
        sWB[j * KP + k] = (j < DE) ? W1[(k + 32) * DE + j] : 0.f;
    }
    if (threadIdx.x < JB) sb1[threadIdx.x] = (threadIdx.x < DE) ? b1[threadIdx.x] : 0.f;
    __syncthreads();

    const int idx = blockIdx.x * 256 + threadIdx.x;   // grid covers NN*JB exactly
    const int n = idx / JB;
    const int j = idx - n * JB;
    const float4* hr = reinterpret_cast<const float4*>(h + (size_t)n * D);
    const float* wa = &sWA[j * KP];
    const float* wb = &sWB[j * KP];
    float a = sb1[j], b = 0.f;
    #pragma unroll
    for (int kk = 0; kk < 8; ++kk) {
        float4 hv = hr[kk];
        a = fmaf(hv.x, wa[4*kk+0], a); a = fmaf(hv.y, wa[4*kk+1], a);
        a = fmaf(hv.z, wa[4*kk+2], a); a = fmaf(hv.w, wa[4*kk+3], a);
        b = fmaf(hv.x, wb[4*kk+0], b); b = fmaf(hv.y, wb[4*kk+1], b);
        b = fmaf(hv.z, wb[4*kk+2], b); b = fmaf(hv.w, wb[4*kk+3], b);
    }
    A[idx] = __float2bfloat16(j < DE ? a : 0.f);
    B[idx] = __float2bfloat16(j < DE ? b : 0.f);
}

// ---------------- edge-order MFMA kernel: one wave per 16-edge tile ----------------
// Lane (er=lane&15, g=lane>>4): builds hidden units j=32c+8g+i for edge er (A-frag),
// W2 register-resident B-frags; C/D: col=lane&15 (output dim), row=4g+reg (edge).
// j=64 rank-1 term folded via shfl+fma. Output scattered with native fp32 atomics
// (64 distinct addresses per atomic wave-inst in unsorted edge order).
__global__ __launch_bounds__(256) void edge_mfma_kernel(
    const int* __restrict__ senders,
    const int* __restrict__ receivers,
    const float* __restrict__ coup,
    const uint4* __restrict__ Au4,
    const uint4* __restrict__ Bu4,
    const float* __restrict__ W1,
    const float* __restrict__ W2,
    const float* __restrict__ b2,
    float* __restrict__ out)
{
    const int lane = threadIdx.x & 63;
    const int g    = lane >> 4;              // k-octet group
    const int er   = lane & 15;              // edge slot / output col

    // ---- per-wave hoisted constants (amortized over ~12 tiles) ----
    float w1c0[8], w1c1[8];
    #pragma unroll
    for (int i = 0; i < 8; ++i) {
        w1c0[i] = W1[64 * DE + 8 * g + i];
        w1c1[i] = W1[64 * DE + 32 + 8 * g + i];
    }
    const float w1c64 = W1[64 * DE + 64];

    short8 WB[2][2];   // WB[chunk][colhalf][i] = W2[32c+8g+i][16hf+er]
    #pragma unroll
    for (int c = 0; c < 2; ++c)
        #pragma unroll
        for (int hf = 0; hf < 2; ++hf)
            #pragma unroll
            for (int i = 0; i < 8; ++i)
                WB[c][hf][i] = f2bf(W2[(32 * c + 8 * g + i) * D + 16 * hf + er]);
    const float w2_64lo = W2[64 * D + er];
    const float w2_64hi = W2[64 * D + 16 + er];
    const float b2lo = b2[er];
    const float b2hi = b2[16 + er];

    const unsigned* Au1 = reinterpret_cast<const unsigned*>(Au4);
    const unsigned* Bu1 = reinterpret_cast<const unsigned*>(Bu4);

    int tile = blockIdx.x * 4 + (threadIdx.x >> 6);
    const int stride = gridDim.x * 4;
    if (tile >= NT) return;

    // ---- prologue: indices + gathers for first tile ----
    int e = tile * 16 + er;
    int s = senders[e];
    int r = receivers[e];
    float ce = coup[e < NC ? e : e - NC];
    uint4 av0 = Au4[(size_t)r * 9 + g];
    uint4 av1 = Au4[(size_t)r * 9 + 4 + g];
    uint4 bv0 = Bu4[(size_t)s * 9 + g];
    uint4 bv1 = Bu4[(size_t)s * 9 + 4 + g];
    unsigned a64u = Au1[(size_t)r * 36 + 32];
    unsigned b64u = Bu1[(size_t)s * 36 + 32];

    while (true) {
        // ---- prefetch next tile's indices (overlaps current compute) ----
        const int tn = tile + stride;
        const bool more = tn < NT;
        int sn = 0, rn = 0;
        float cn = 0.f;
        if (more) {
            const int en = tn * 16 + er;
            sn = senders[en];
            rn = receivers[en];
            cn = coup[en < NC ? en : en - NC];
        }

        // ---- build A-frags for current tile ----
        short8 A0, A1;
        {
            float2 ta, tb;
            ta = bf2(av0.x); tb = bf2(bv0.x);
            A0[0] = f2bf(selu_f(fmaf(ce, w1c0[0], ta.x + tb.x)));
            A0[1] = f2bf(selu_f(fmaf(ce, w1c0[1], ta.y + tb.y)));
            ta = bf2(av0.y); tb = bf2(bv0.y);
            A0[2] = f2bf(selu_f(fmaf(ce, w1c0[2], ta.x + tb.x)));
            A0[3] = f2bf(selu_f(fmaf(ce, w1c0[3], ta.y + tb.y)));
            ta = bf2(av0.z); tb = bf2(bv0.z);
            A0[4] = f2bf(selu_f(fmaf(ce, w1c0[4], ta.x + tb.x)));
            A0[5] = f2bf(selu_f(fmaf(ce, w1c0[5], ta.y + tb.y)));
            ta = bf2(av0.w); tb = bf2(bv0.w);
            A0[6] = f2bf(selu_f(fmaf(ce, w1c0[6], ta.x + tb.x)));
            A0[7] = f2bf(selu_f(fmaf(ce, w1c0[7], ta.y + tb.y)));
            ta = bf2(av1.x); tb = bf2(bv1.x);
            A1[0] = f2bf(selu_f(fmaf(ce, w1c1[0], ta.x + tb.x)));
            A1[1] = f2bf(selu_f(fmaf(ce, w1c1[1], ta.y + tb.y)));
            ta = bf2(av1.y); tb = bf2(bv1.y);
            A1[2] = f2bf(selu_f(fmaf(ce, w1c1[2], ta.x + tb.x)));
            A1[3] = f2bf(selu_f(fmaf(ce, w1c1[3], ta.y + tb.y)));
            ta = bf2(av1.z); tb = bf2(bv1.z);
            A1[4] = f2bf(selu_f(fmaf(ce, w1c1[4], ta.x + tb.x)));
            A1[5] = f2bf(selu_f(fmaf(ce, w1c1[5], ta.y + tb.y)));
            ta = bf2(av1.w); tb = bf2(bv1.w);
            A1[6] = f2bf(selu_f(fmaf(ce, w1c1[6], ta.x + tb.x)));
            A1[7] = f2bf(selu_f(fmaf(ce, w1c1[7], ta.y + tb.y)));
        }
        const float h64 = selu_f(fmaf(ce, w1c64, bf2(a64u).x + bf2(b64u).x));
        const int rcur = r;

        // ---- issue next tile's gathers (latency hides under MFMA+epilogue) ----
        uint4 av0n, av1n, bv0n, bv1n;
        unsigned a64n = 0u, b64n = 0u;
        if (more) {
            av0n = Au4[(size_t)rn * 9 + g];
            av1n = Au4[(size_t)rn * 9 + 4 + g];
            bv0n = Bu4[(size_t)sn * 9 + g];
            bv1n = Bu4[(size_t)sn * 9 + 4 + g];
            a64n = Au1[(size_t)rn * 36 + 32];
            b64n = Bu1[(size_t)sn * 36 + 32];
        }

        // ---- MFMA: 64x(16 edges) x 32 dims ----
        f32x4 Clo = {0.f, 0.f, 0.f, 0.f};
        f32x4 Chi = {0.f, 0.f, 0.f, 0.f};
        Clo = __builtin_amdgcn_mfma_f32_16x16x32_bf16(A0, WB[0][0], Clo, 0, 0, 0);
        Clo = __builtin_amdgcn_mfma_f32_16x16x32_bf16(A1, WB[1][0], Clo, 0, 0, 0);
        Chi = __builtin_amdgcn_mfma_f32_16x16x32_bf16(A0, WB[0][1], Chi, 0, 0, 0);
        Chi = __builtin_amdgcn_mfma_f32_16x16x32_bf16(A1, WB[1][1], Chi, 0, 0, 0);

        // ---- j=64 fold + outer selu + atomic scatter ----
        #pragma unroll
        for (int q = 0; q < 4; ++q) {
            const int m = 4 * g + q;                 // edge slot of C row q
            const float hm = __shfl(h64, m);
            const int   rq = __shfl(rcur, m);
            const float mlo = selu_f(fmaf(hm, w2_64lo, Clo[q]) + b2lo);
            const float mhi = selu_f(fmaf(hm, w2_64hi, Chi[q]) + b2hi);
            unsafeAtomicAdd(&out[(size_t)rq * D + er], mlo);
            unsafeAtomicAdd(&out[(size_t)rq * D + 16 + er], mhi);
        }

        if (!more) break;
        tile = tn; s = sn; r = rn; ce = cn;
        av0 = av0n; av1 = av1n; bv0 = bv0n; bv1 = bv1n;
        a64u = a64n; b64u = b64n;
    }
}

__global__ __launch_bounds__(256) void relu_kernel(float* __restrict__ out) {
    const int i = blockIdx.x * 256 + threadIdx.x;
    float4* p = reinterpret_cast<float4*>(out);
    float4 v = p[i];
    v.x = fmaxf(v.x, 0.f); v.y = fmaxf(v.y, 0.f);
    v.z = fmaxf(v.z, 0.f); v.w = fmaxf(v.w, 0.f);
    p[i] = v;
}

// ---------------- fallback (ws too small): monolithic round-1 kernel ----------
__global__ __launch_bounds__(256) void edge_msg_fallback(
    const float* __restrict__ h, const float* __restrict__ coup,
    const float* __restrict__ W1, const float* __restrict__ b1,
    const float* __restrict__ W2, const float* __restrict__ b2,
    const int* __restrict__ senders, const int* __restrict__ receivers,
    float* __restrict__ out)
{
    __shared__ float sW1t[DE * W1_LD];
    __shared__ float sW2[DE * D];
    __shared__ float sb1[DE];
    __shared__ float sb2[D];
    for (int i = threadIdx.x; i < DE * DE; i += 256) {
        int k = i / DE, j = i - k * DE;
        sW1t[j * W1_LD + k] = W1[i];
    }
    for (int i = threadIdx.x; i < DE * D; i += 256) sW2[i] = W2[i];
    if (threadIdx.x < DE) sb1[threadIdx.x] = b1[threadIdx.x];
    if (threadIdx.x >= 128 && threadIdx.x < 128 + D) sb2[threadIdx.x - 128] = b2[threadIdx.x - 128];
    __syncthreads();
    const int e = blockIdx.x * 256 + threadIdx.x;
    const int s = senders[e];
    const int r = receivers[e];
    float edgef[DE];
    const float4* hr = reinterpret_cast<const float4*>(h + (size_t)r * D);
    const float4* hs = reinterpret_cast<const float4*>(h + (size_t)s * D);
    #pragma unroll
    for (int i = 0; i < 8; ++i) {
        float4 v = hr[i];
        edgef[4*i] = v.x; edgef[4*i+1] = v.y; edgef[4*i+2] = v.z; edgef[4*i+3] = v.w;
    }
    #pragma unroll
    for (int i = 0; i < 8; ++i) {
        float4 v = hs[i];
        edgef[D+4*i] = v.x; edgef[D+4*i+1] = v.y; edgef[D+4*i+2] = v.z; edgef[D+4*i+3] = v.w;
    }
    edgef[2*D] = coup[e < NC ? e : e - NC];
    float acc[D];
    #pragma unroll
    for (int d2 = 0; d2 < D; ++d2) acc[d2] = sb2[d2];
    for (int j = 0; j < DE; ++j) {
        const float* wrow = &sW1t[j * W1_LD];
        float p0 = 0.f, p1 = 0.f, p2 = 0.f, p3 = 0.f;
        #pragma unroll
        for (int k = 0; k < 64; k += 4) {
            p0 = fmaf(edgef[k], wrow[k], p0);
            p1 = fmaf(edgef[k+1], wrow[k+1], p1);
            p2 = fmaf(edgef[k+2], wrow[k+2], p2);
            p3 = fmaf(edgef[k+3], wrow[k+3], p3);
        }
        float hj = selu_f(sb1[j] + fmaf(edgef[64], wrow[64], (p0+p1)+(p2+p3)));
        const float* w2row = &sW2[j * D];
        #pragma unroll
        for (int d2 = 0; d2 < D; ++d2) acc[d2] = fmaf(hj, w2row[d2], acc[d2]);
    }
    float* op = out + (size_t)r * D;
    #pragma unroll
    for (int d2 = 0; d2 < D; ++d2) unsafeAtomicAdd(op + d2, selu_f(acc[d2]));
}

extern "C" void kernel_launch(void* const* d_in, const int* in_sizes, int n_in,
                              void* d_out, int out_size, void* d_ws, size_t ws_size,
                              hipStream_t stream) {
    const float* h    = (const float*)d_in[0];
    const float* coup = (const float*)d_in[1];
    const float* W1   = (const float*)d_in[2];
    const float* b1   = (const float*)d_in[3];
    const float* W2   = (const float*)d_in[4];
    const float* b2   = (const float*)d_in[5];
    // d_in[6..9] = Wq, bq, Wk, bk: unused — softmax over a size-1 axis is 1.0
    const int* senders   = (const int*)d_in[10];
    const int* receivers = (const int*)d_in[11];
    float* out = (float*)d_out;

    hipMemsetAsync(d_out, 0, (size_t)out_size * sizeof(float), stream);

    if (ws_size >= (size_t)WS_NEED) {
        char* ws = (char*)d_ws;
        __hip_bfloat16* Atab = (__hip_bfloat16*)(ws + OFF_A);
        __hip_bfloat16* Btab = (__hip_bfloat16*)(ws + OFF_B);

        precompute_kernel<<<NN * JB / 256, 256, 0, stream>>>(h, W1, b1, Atab, Btab);
        edge_mfma_kernel<<<2048, 256, 0, stream>>>(
            senders, receivers, coup,
            (const uint4*)Atab, (const uint4*)Btab,
            W1, W2, b2, out);
    } else {
        edge_msg_fallback<<<NE / 256, 256, 0, stream>>>(
            h, coup, W1, b1, W2, b2, senders, receivers, out);
    }
    relu_kernel<<<out_size / 4 / 256, 256, 0, stream>>>(out);
}

// Round 9
// 282.076 us; speedup vs baseline: 13.5529x; 1.0602x over previous
//
#include <hip/hip_runtime.h>
#include <hip/hip_bf16.h>

#define NN 100000
#define NE 1600000
#define NC 800000
#define D  32
#define DE 65
#define JB 64     // bf16 elements per table row: 128B, line-aligned; 8 uint4
#define KP 33     // LDS k-stride in precompute (conflict-free: bank=(j+k)%32)
#define W1_LD 68  // fallback kernel stride
#define NT (NE / 16)   // 100000 full 16-edge tiles (NE % 16 == 0)

// ---- ws byte offsets (128B-aligned tables) ----
#define OFF_A   0u                  // bf16[NN*64]  A table (b1 folded), 128B rows
#define OFF_B   12800000u           // bf16[NN*64]  B table
#define OFF_A64 25600000u           // bf16[NN]     A j=64 column (b1[64] folded)
#define OFF_B64 25800000u           // bf16[NN]     B j=64 column
#define WS_NEED 26000000u

typedef __attribute__((ext_vector_type(8))) short short8;
typedef __attribute__((ext_vector_type(4))) float f32x4;

__device__ __forceinline__ float selu_f(float x) {
    // branch-free: x>0 -> scale*x ; x<0 -> scale*alpha*(exp(x)-1)
    float p = fmaxf(x, 0.f);
    float m = fminf(x, 0.f);
    return fmaf(1.7580993408473766f, __expf(m) - 1.f, 1.0507009873554805f * p);
}

__device__ __forceinline__ float2 bf2(unsigned int u) {
    // two packed bf16 -> two floats (element 0 in low 16 bits)
    return make_float2(__uint_as_float(u << 16), __uint_as_float(u & 0xffff0000u));
}

__device__ __forceinline__ float bfs(unsigned short u) {
    return __uint_as_float(((unsigned)u) << 16);
}

__device__ __forceinline__ short f2bf(float x) {
    union { __hip_bfloat16 h; short s; } u;
    u.h = __float2bfloat16(x);
    return u.s;
}

// ---------------- per-node layer-1 halves (j<64), bf16, 128B rows ----------------
// A[n][j] = b1[j] + sum_k h[n][k]*W1[k][j]      (k in [0,32))
// B[n][j] =          sum_k h[n][k]*W1[32+k][j]
__global__ __launch_bounds__(256) void precompute_kernel(
    const float* __restrict__ h, const float* __restrict__ W1,
    const float* __restrict__ b1,
    __hip_bfloat16* __restrict__ A, __hip_bfloat16* __restrict__ B)
{
    __shared__ float sWA[JB * KP];
    __shared__ float sWB[JB * KP];
    __shared__ float sb1[JB];
    for (int i = threadIdx.x; i < JB * 32; i += 256) {
        int j = i >> 5, k = i & 31;
        sWA[j * KP + k] = W1[k * DE + j];
        sWB[j * KP + k] = W1[(k + 32) * DE + j];
    }
    if (threadIdx.x < JB) sb1[threadIdx.x] = b1[threadIdx.x];
    __syncthreads();

    const int idx = blockIdx.x * 256 + threadIdx.x;   // grid covers NN*JB exactly
    const int n = idx >> 6;
    const int j = idx & 63;
    const float4* hr = reinterpret_cast<const float4*>(h + (size_t)n * D);
    const float* wa = &sWA[j * KP];
    const float* wb = &sWB[j * KP];
    float a = sb1[j], b = 0.f;
    #pragma unroll
    for (int kk = 0; kk < 8; ++kk) {
        float4 hv = hr[kk];
        a = fmaf(hv.x, wa[4*kk+0], a); a = fmaf(hv.y, wa[4*kk+1], a);
        a = fmaf(hv.z, wa[4*kk+2], a); a = fmaf(hv.w, wa[4*kk+3], a);
        b = fmaf(hv.x, wb[4*kk+0], b); b = fmaf(hv.y, wb[4*kk+1], b);
        b = fmaf(hv.z, wb[4*kk+2], b); b = fmaf(hv.w, wb[4*kk+3], b);
    }
    A[idx] = __float2bfloat16(a);
    B[idx] = __float2bfloat16(b);
}

// ---------------- j=64 column (tiny side tables, L2-resident) ----------------
__global__ __launch_bounds__(256) void precompute64_kernel(
    const float* __restrict__ h, const float* __restrict__ W1,
    const float* __restrict__ b1,
    unsigned short* __restrict__ A64, unsigned short* __restrict__ B64)
{
    __shared__ float w1a[32], w1b[32];
    if (threadIdx.x < 32) {
        w1a[threadIdx.x] = W1[threadIdx.x * DE + 64];
        w1b[threadIdx.x] = W1[(threadIdx.x + 32) * DE + 64];
    }
    __syncthreads();
    const int n = blockIdx.x * 256 + threadIdx.x;
    if (n >= NN) return;
    const float4* hr = reinterpret_cast<const float4*>(h + (size_t)n * D);
    float a = b1[64], b = 0.f;
    #pragma unroll
    for (int kk = 0; kk < 8; ++kk) {
        float4 hv = hr[kk];
        a = fmaf(hv.x, w1a[4*kk+0], a); a = fmaf(hv.y, w1a[4*kk+1], a);
        a = fmaf(hv.z, w1a[4*kk+2], a); a = fmaf(hv.w, w1a[4*kk+3], a);
        b = fmaf(hv.x, w1b[4*kk+0], b); b = fmaf(hv.y, w1b[4*kk+1], b);
        b = fmaf(hv.z, w1b[4*kk+2], b); b = fmaf(hv.w, w1b[4*kk+3], b);
    }
    A64[n] = (unsigned short)f2bf(a);
    B64[n] = (unsigned short)f2bf(b);
}

// ---------------- edge-order MFMA kernel: one wave per 16-edge tile ----------------
// Lane (er=lane&15, g=lane>>4): builds hidden units j=32c+8g+i for edge er (A-frag),
// W2 register-resident B-frags; C/D: col=lane&15 (output dim), row=4g+reg (edge).
// j=64 rank-1 term folded via shfl+fma. Output scattered with native fp32 atomics
// (64 distinct addresses per atomic wave-inst in unsorted edge order).
__global__ __launch_bounds__(256) void edge_mfma_kernel(
    const int* __restrict__ senders,
    const int* __restrict__ receivers,
    const float* __restrict__ coup,
    const uint4* __restrict__ Au4,
    const uint4* __restrict__ Bu4,
    const unsigned short* __restrict__ A64,
    const unsigned short* __restrict__ B64,
    const float* __restrict__ W1,
    const float* __restrict__ W2,
    const float* __restrict__ b2,
    float* __restrict__ out)
{
    const int lane = threadIdx.x & 63;
    const int g    = lane >> 4;              // k-octet group
    const int er   = lane & 15;              // edge slot / output col

    // ---- per-wave hoisted constants (amortized over ~12 tiles) ----
    float w1c0[8], w1c1[8];
    #pragma unroll
    for (int i = 0; i < 8; ++i) {
        w1c0[i] = W1[64 * DE + 8 * g + i];
        w1c1[i] = W1[64 * DE + 32 + 8 * g + i];
    }
    const float w1c64 = W1[64 * DE + 64];

    short8 WB[2][2];   // WB[chunk][colhalf][i] = W2[32c+8g+i][16hf+er]
    #pragma unroll
    for (int c = 0; c < 2; ++c)
        #pragma unroll
        for (int hf = 0; hf < 2; ++hf)
            #pragma unroll
            for (int i = 0; i < 8; ++i)
                WB[c][hf][i] = f2bf(W2[(32 * c + 8 * g + i) * D + 16 * hf + er]);
    const float w2_64lo = W2[64 * D + er];
    const float w2_64hi = W2[64 * D + 16 + er];
    const float b2lo = b2[er];
    const float b2hi = b2[16 + er];

    int tile = blockIdx.x * 4 + (threadIdx.x >> 6);
    const int stride = gridDim.x * 4;
    if (tile >= NT) return;

    // ---- prologue: indices + gathers for first tile ----
    int e = tile * 16 + er;
    int s = senders[e];
    int r = receivers[e];
    float ce = coup[e < NC ? e : e - NC];
    uint4 av0 = Au4[(size_t)r * 8 + g];
    uint4 av1 = Au4[(size_t)r * 8 + 4 + g];
    uint4 bv0 = Bu4[(size_t)s * 8 + g];
    uint4 bv1 = Bu4[(size_t)s * 8 + 4 + g];
    unsigned short a64u = A64[r];
    unsigned short b64u = B64[s];

    while (true) {
        // ---- prefetch next tile's indices (overlaps current compute) ----
        const int tn = tile + stride;
        const bool more = tn < NT;
        int sn = 0, rn = 0;
        float cn = 0.f;
        if (more) {
            const int en = tn * 16 + er;
            sn = senders[en];
            rn = receivers[en];
            cn = coup[en < NC ? en : en - NC];
        }

        // ---- build A-frags for current tile ----
        short8 A0, A1;
        {
            float2 ta, tb;
            ta = bf2(av0.x); tb = bf2(bv0.x);
            A0[0] = f2bf(selu_f(fmaf(ce, w1c0[0], ta.x + tb.x)));
            A0[1] = f2bf(selu_f(fmaf(ce, w1c0[1], ta.y + tb.y)));
            ta = bf2(av0.y); tb = bf2(bv0.y);
            A0[2] = f2bf(selu_f(fmaf(ce, w1c0[2], ta.x + tb.x)));
            A0[3] = f2bf(selu_f(fmaf(ce, w1c0[3], ta.y + tb.y)));
            ta = bf2(av0.z); tb = bf2(bv0.z);
            A0[4] = f2bf(selu_f(fmaf(ce, w1c0[4], ta.x + tb.x)));
            A0[5] = f2bf(selu_f(fmaf(ce, w1c0[5], ta.y + tb.y)));
            ta = bf2(av0.w); tb = bf2(bv0.w);
            A0[6] = f2bf(selu_f(fmaf(ce, w1c0[6], ta.x + tb.x)));
            A0[7] = f2bf(selu_f(fmaf(ce, w1c0[7], ta.y + tb.y)));
            ta = bf2(av1.x); tb = bf2(bv1.x);
            A1[0] = f2bf(selu_f(fmaf(ce, w1c1[0], ta.x + tb.x)));
            A1[1] = f2bf(selu_f(fmaf(ce, w1c1[1], ta.y + tb.y)));
            ta = bf2(av1.y); tb = bf2(bv1.y);
            A1[2] = f2bf(selu_f(fmaf(ce, w1c1[2], ta.x + tb.x)));
            A1[3] = f2bf(selu_f(fmaf(ce, w1c1[3], ta.y + tb.y)));
            ta = bf2(av1.z); tb = bf2(bv1.z);
            A1[4] = f2bf(selu_f(fmaf(ce, w1c1[4], ta.x + tb.x)));
            A1[5] = f2bf(selu_f(fmaf(ce, w1c1[5], ta.y + tb.y)));
            ta = bf2(av1.w); tb = bf2(bv1.w);
            A1[6] = f2bf(selu_f(fmaf(ce, w1c1[6], ta.x + tb.x)));
            A1[7] = f2bf(selu_f(fmaf(ce, w1c1[7], ta.y + tb.y)));
        }
        const float h64 = selu_f(fmaf(ce, w1c64, bfs(a64u) + bfs(b64u)));
        const int rcur = r;

        // ---- issue next tile's gathers (latency hides under MFMA+epilogue) ----
        uint4 av0n, av1n, bv0n, bv1n;
        unsigned short a64n = 0, b64n = 0;
        if (more) {
            av0n = Au4[(size_t)rn * 8 + g];
            av1n = Au4[(size_t)rn * 8 + 4 + g];
            bv0n = Bu4[(size_t)sn * 8 + g];
            bv1n = Bu4[(size_t)sn * 8 + 4 + g];
            a64n = A64[rn];
            b64n = B64[sn];
        }

        // ---- MFMA: (16 edges) x 32 dims, K=64 ----
        f32x4 Clo = {0.f, 0.f, 0.f, 0.f};
        f32x4 Chi = {0.f, 0.f, 0.f, 0.f};
        Clo = __builtin_amdgcn_mfma_f32_16x16x32_bf16(A0, WB[0][0], Clo, 0, 0, 0);
        Clo = __builtin_amdgcn_mfma_f32_16x16x32_bf16(A1, WB[1][0], Clo, 0, 0, 0);
        Chi = __builtin_amdgcn_mfma_f32_16x16x32_bf16(A0, WB[0][1], Chi, 0, 0, 0);
        Chi = __builtin_amdgcn_mfma_f32_16x16x32_bf16(A1, WB[1][1], Chi, 0, 0, 0);

        // ---- j=64 fold + outer selu + atomic scatter ----
        #pragma unroll
        for (int q = 0; q < 4; ++q) {
            const int m = 4 * g + q;                 // edge slot of C row q
            const float hm = __shfl(h64, m);
            const int   rq = __shfl(rcur, m);
            const float mlo = selu_f(fmaf(hm, w2_64lo, Clo[q]) + b2lo);
            const float mhi = selu_f(fmaf(hm, w2_64hi, Chi[q]) + b2hi);
            unsafeAtomicAdd(&out[(size_t)rq * D + er], mlo);
            unsafeAtomicAdd(&out[(size_t)rq * D + 16 + er], mhi);
        }

        if (!more) break;
        tile = tn; s = sn; r = rn; ce = cn;
        av0 = av0n; av1 = av1n; bv0 = bv0n; bv1 = bv1n;
        a64u = a64n; b64u = b64n;
    }
}

__global__ __launch_bounds__(256) void relu_kernel(float* __restrict__ out) {
    const int i = blockIdx.x * 256 + threadIdx.x;
    float4* p = reinterpret_cast<float4*>(out);
    float4 v = p[i];
    v.x = fmaxf(v.x, 0.f); v.y = fmaxf(v.y, 0.f);
    v.z = fmaxf(v.z, 0.f); v.w = fmaxf(v.w, 0.f);
    p[i] = v;
}

// ---------------- fallback (ws too small): monolithic round-1 kernel ----------
__global__ __launch_bounds__(256) void edge_msg_fallback(
    const float* __restrict__ h, const float* __restrict__ coup,
    const float* __restrict__ W1, const float* __restrict__ b1,
    const float* __restrict__ W2, const float* __restrict__ b2,
    const int* __restrict__ senders, const int* __restrict__ receivers,
    float* __restrict__ out)
{
    __shared__ float sW1t[DE * W1_LD];
    __shared__ float sW2[DE * D];
    __shared__ float sb1[DE];
    __shared__ float sb2[D];
    for (int i = threadIdx.x; i < DE * DE; i += 256) {
        int k = i / DE, j = i - k * DE;
        sW1t[j * W1_LD + k] = W1[i];
    }
    for (int i = threadIdx.x; i < DE * D; i += 256) sW2[i] = W2[i];
    if (threadIdx.x < DE) sb1[threadIdx.x] = b1[threadIdx.x];
    if (threadIdx.x >= 128 && threadIdx.x < 128 + D) sb2[threadIdx.x - 128] = b2[threadIdx.x - 128];
    __syncthreads();
    const int e = blockIdx.x * 256 + threadIdx.x;
    const int s = senders[e];
    const int r = receivers[e];
    float edgef[DE];
    const float4* hr = reinterpret_cast<const float4*>(h + (size_t)r * D);
    const float4* hs = reinterpret_cast<const float4*>(h + (size_t)s * D);
    #pragma unroll
    for (int i = 0; i < 8; ++i) {
        float4 v = hr[i];
        edgef[4*i] = v.x; edgef[4*i+1] = v.y; edgef[4*i+2] = v.z; edgef[4*i+3] = v.w;
    }
    #pragma unroll
    for (int i = 0; i < 8; ++i) {
        float4 v = hs[i];
        edgef[D+4*i] = v.x; edgef[D+4*i+1] = v.y; edgef[D+4*i+2] = v.z; edgef[D+4*i+3] = v.w;
    }
    edgef[2*D] = coup[e < NC ? e : e - NC];
    float acc[D];
    #pragma unroll
    for (int d2 = 0; d2 < D; ++d2) acc[d2] = sb2[d2];
    for (int j = 0; j < DE; ++j) {
        const float* wrow = &sW1t[j * W1_LD];
        float p0 = 0.f, p1 = 0.f, p2 = 0.f, p3 = 0.f;
        #pragma unroll
        for (int k = 0; k < 64; k += 4) {
            p0 = fmaf(edgef[k], wrow[k], p0);
            p1 = fmaf(edgef[k+1], wrow[k+1], p1);
            p2 = fmaf(edgef[k+2], wrow[k+2], p2);
            p3 = fmaf(edgef[k+3], wrow[k+3], p3);
        }
        float hj = selu_f(sb1[j] + fmaf(edgef[64], wrow[64], (p0+p1)+(p2+p3)));
        const float* w2row = &sW2[j * D];
        #pragma unroll
        for (int d2 = 0; d2 < D; ++d2) acc[d2] = fmaf(hj, w2row[d2], acc[d2]);
    }
    float* op = out + (size_t)r * D;
    #pragma unroll
    for (int d2 = 0; d2 < D; ++d2) unsafeAtomicAdd(op + d2, selu_f(acc[d2]));
}

extern "C" void kernel_launch(void* const* d_in, const int* in_sizes, int n_in,
                              void* d_out, int out_size, void* d_ws, size_t ws_size,
                              hipStream_t stream) {
    const float* h    = (const float*)d_in[0];
    const float* coup = (const float*)d_in[1];
    const float* W1   = (const float*)d_in[2];
    const float* b1   = (const float*)d_in[3];
    const float* W2   = (const float*)d_in[4];
    const float* b2   = (const float*)d_in[5];
    // d_in[6..9] = Wq, bq, Wk, bk: unused — softmax over a size-1 axis is 1.0
    const int* senders   = (const int*)d_in[10];
    const int* receivers = (const int*)d_in[11];
    float* out = (float*)d_out;

    hipMemsetAsync(d_out, 0, (size_t)out_size * sizeof(float), stream);

    if (ws_size >= (size_t)WS_NEED) {
        char* ws = (char*)d_ws;
        __hip_bfloat16* Atab = (__hip_bfloat16*)(ws + OFF_A);
        __hip_bfloat16* Btab = (__hip_bfloat16*)(ws + OFF_B);
        unsigned short* A64  = (unsigned short*)(ws + OFF_A64);
        unsigned short* B64  = (unsigned short*)(ws + OFF_B64);

        precompute_kernel<<<NN * JB / 256, 256, 0, stream>>>(h, W1, b1, Atab, Btab);
        precompute64_kernel<<<(NN + 255) / 256, 256, 0, stream>>>(h, W1, b1, A64, B64);
        edge_mfma_kernel<<<2048, 256, 0, stream>>>(
            senders, receivers, coup,
            (const uint4*)Atab, (const uint4*)Btab, A64, B64,
            W1, W2, b2, out);
    } else {
        edge_msg_fallback<<<NE / 256, 256, 0, stream>>>(
            h, coup, W1, b1, W2, b2, senders, receivers, out);
    }
    relu_kernel<<<out_size / 4 / 256, 256, 0, stream>>>(out);
}